// Round 3
// baseline (87319.482 us; speedup 1.0000x reference)
//
#include <hip/hip_runtime.h>
#include <hip/hip_bf16.h>

// Elman RNN correctness ANCHOR (round 3). VOCAB=50257, EMB=256, HID=512,
// OUT=2, B=128, T=512. Deliberately boring: no MFMA, no vector loads, no
// double-buffering, library tanhf, f32 accumulation. Runtime dtype detection
// for (x: int32 vs int64) and (floats: bf16 vs f32) — data-dependent but
// constant across calls, so graph-safe.
//
// 64 blocks x 512 threads; block g owns batches {2g, 2g+1}; thread tid owns
// output column n = tid. Two barriers per timestep.

#define VOCAB   50257
#define T_STEPS 512
#define HID     512
#define EMB     256
#define B_PER   2

__device__ inline float ldf(const void* p, long i, bool f32) {
    if (f32) return ((const float*)p)[i];
    unsigned bits = ((unsigned)((const unsigned short*)p)[i]) << 16;
    return __uint_as_float(bits);
}

__device__ inline void stf(void* p, int i, float v, bool f32) {
    if (f32) { ((float*)p)[i] = v; return; }
    unsigned b = __float_as_uint(v);
    unsigned r = (b + 0x7fffu + ((b >> 16) & 1u)) >> 16;   // RNE bf16
    ((unsigned short*)p)[i] = (unsigned short)r;
}

__device__ inline int get_tok(const int* x, int idx, bool x64) {
    unsigned u = (unsigned)(x64 ? x[2 * idx] : x[idx]);
    return (u < (unsigned)VOCAB) ? (int)u : 0;   // clamp: insurance, not expected
}

__global__ __launch_bounds__(512) void rnn_anchor(
    const int* __restrict__ x, const void* __restrict__ emb,
    const void* __restrict__ Ww, const void* __restrict__ Wb,
    const void* __restrict__ Uw, const void* __restrict__ Ub,
    const void* __restrict__ Vw, const void* __restrict__ Vb,
    void* __restrict__ out)
{
    __shared__ float h_s[2][B_PER][HID];     // ping-pong hidden state, 8 KB
    __shared__ float xe_s[B_PER][EMB];       // current-step embeddings, 2 KB
    __shared__ int   flags_s;

    const int tid = threadIdx.x;
    const int b0  = blockIdx.x * B_PER;

    if (tid == 0) {
        // floats f32? emb row 0 is all-zero (padding_idx). If underlying f32,
        // bf16-view elements [256,320) are still row-0 zero bytes; if bf16,
        // they are row-1 random normals (never all zero).
        int allz = 1;
        const unsigned short* e16 = (const unsigned short*)emb;
        for (int i = 256; i < 320; ++i) allz &= (e16[i] == 0);
        // x int64? high words of positive int64 tokens are zero at odd int32
        // indices. 8 probes => false-positive P ~ (1/50257)^8.
        int x64 = 1;
        for (int j = 1; j < 16; j += 2) x64 &= (x[j] == 0);
        flags_s = allz | (x64 << 1);
    }
    __syncthreads();
    const bool f32w = (flags_s & 1) != 0;
    const bool x64  = (flags_s & 2) != 0;

    const int n = tid;                        // output column owned by thread
    const float bias = ldf(Wb, n, f32w) + ldf(Ub, n, f32w);

    // h0 = 0
    for (int b = 0; b < B_PER; ++b) h_s[0][b][n] = 0.0f;

    for (int t = 0; t < T_STEPS; ++t) {
        // gather xe for this step (single-buffered; barrier-protected)
        {
            int i = tid;                       // 512 threads, 512 elements
            int b = i >> 8, c = i & 255;
            int tok = get_tok(x, (b0 + b) * T_STEPS + t, x64);
            xe_s[b][c] = ldf(emb, (long)tok * EMB + c, f32w);
        }
        __syncthreads();                       // xe ready; h_s[cur] ready

        float acc0 = bias, acc1 = bias;
        const long wrow = (long)n * EMB;
#pragma unroll 8
        for (int k = 0; k < EMB; ++k) {
            float w = ldf(Ww, wrow + k, f32w);
            acc0 += xe_s[0][k] * w;
            acc1 += xe_s[1][k] * w;
        }
        const long urow = (long)n * HID;
        const float* hc0 = h_s[t & 1][0];
        const float* hc1 = h_s[t & 1][1];
#pragma unroll 8
        for (int k = 0; k < HID; ++k) {
            float u = ldf(Uw, urow + k, f32w);
            acc0 += hc0[k] * u;
            acc1 += hc1[k] * u;
        }
        h_s[(t + 1) & 1][0][n] = tanhf(acc0);
        h_s[(t + 1) & 1][1][n] = tanhf(acc1);
        __syncthreads();                       // h_new complete; xe_s reusable
    }

    // logits = hT @ Vw^T + Vb ; final h is h_s[0] (T even)
    if (tid < 2 * B_PER) {
        int b = tid >> 1, o = tid & 1;
        float s = ldf(Vb, o, f32w);
        for (int k = 0; k < HID; ++k)
            s += h_s[0][b][k] * ldf(Vw, (long)o * HID + k, f32w);
        stf(out, (b0 + b) * 2 + o, s, f32w);
    }
}

extern "C" void kernel_launch(void* const* d_in, const int* in_sizes, int n_in,
                              void* d_out, int out_size, void* d_ws, size_t ws_size,
                              hipStream_t stream) {
    const int* x = (const int*)d_in[0];
    rnn_anchor<<<64, 512, 0, stream>>>(
        x, d_in[1], d_in[2], d_in[3], d_in[4], d_in[5], d_in[6], d_in[7], d_out);
}

// Round 4
// 87224.188 us; speedup vs baseline: 1.0011x; 1.0011x over previous
//
#include <hip/hip_runtime.h>
#include <hip/hip_bf16.h>
#include <math.h>

// Elman RNN. VOCAB=50257, EMB=256, HID=512, OUT=2, B=128, T=512.
// R4 strategy: MFMA fused scan (8 blocks x 1024 thr, weights streamed from L2,
// no workspace) + fixup kernel that recomputes any batch-group whose outputs
// are NaN using the round-3 PROVEN anchor math (guaranteed pass).

#define VOCAB   50257
#define T_STEPS 512
#define HID     512
#define EMB     256
#define XPAD    264   // xe row stride (bf16): 528 B, 16B-aligned
#define HPAD    528   // h row stride (bf16): 1056 B, 16B-aligned

typedef __bf16 bf16x8 __attribute__((ext_vector_type(8)));
typedef float  f32x4  __attribute__((ext_vector_type(4)));

__device__ inline float ldf(const void* p, long i, bool f32) {
    if (f32) return ((const float*)p)[i];
    unsigned bits = ((unsigned)((const unsigned short*)p)[i]) << 16;
    return __uint_as_float(bits);
}
__device__ inline void stf(void* p, int i, float v, bool f32) {
    if (f32) { ((float*)p)[i] = v; return; }
    unsigned b = __float_as_uint(v);
    unsigned r = (b + 0x7fffu + ((b >> 16) & 1u)) >> 16;   // RNE bf16
    ((unsigned short*)p)[i] = (unsigned short)r;
}
__device__ inline int get_tok(const int* x, int idx, bool x64) {
    unsigned u = (unsigned)(x64 ? x[2 * idx] : x[idx]);
    return (u < (unsigned)VOCAB) ? (int)u : 0;
}
// thread-0 dtype probes (data-dependent but constant across calls -> graph-safe)
__device__ inline int detect_flags(const int* x, const void* emb) {
    int allz = 1;  // floats f32?  emb row0 zero => bf16-view elems [256,320) zero
    const unsigned short* e16 = (const unsigned short*)emb;
    for (int i = 256; i < 320; ++i) allz &= (e16[i] == 0);
    int x64 = 1;   // x int64?  odd int32 words all zero
    for (int j = 1; j < 16; j += 2) x64 &= (x[j] == 0);
    return allz | (x64 << 1);
}

// ---------------- fast path: fused MFMA scan (bf16 weights only) ------------
__global__ __launch_bounds__(1024, 4) void scan_mfma(
    const int* __restrict__ x, const void* __restrict__ embv,
    const void* __restrict__ Wwv, const void* __restrict__ Wbv,
    const void* __restrict__ Uwv, const void* __restrict__ Ubv,
    const void* __restrict__ Vwv, const void* __restrict__ Vbv,
    void* __restrict__ outv)
{
    __shared__ __align__(16) __hip_bfloat16 xe_s[16][XPAD];
    __shared__ __align__(16) __hip_bfloat16 hbuf[2][16][HPAD];
    __shared__ int flags_s;

    const int tid = threadIdx.x;
    const int b0  = blockIdx.x * 16;

    if (tid == 0) flags_s = detect_flags(x, embv);
    __syncthreads();
    const bool f32w = (flags_s & 1) != 0;
    const bool x64  = (flags_s & 2) != 0;

    if (f32w) {   // not the expected world: punt, fixup recomputes everything
        if (tid < 32) ((float*)outv)[b0 * 2 + tid] = __uint_as_float(0x7FC00000u);
        return;
    }

    const __hip_bfloat16* emb = (const __hip_bfloat16*)embv;
    const __hip_bfloat16* Ww  = (const __hip_bfloat16*)Wwv;
    const __hip_bfloat16* Wb  = (const __hip_bfloat16*)Wbv;
    const __hip_bfloat16* Uw  = (const __hip_bfloat16*)Uwv;
    const __hip_bfloat16* Ub  = (const __hip_bfloat16*)Ubv;
    const __hip_bfloat16* Vw  = (const __hip_bfloat16*)Vwv;
    const __hip_bfloat16* Vb  = (const __hip_bfloat16*)Vbv;

    const int w = tid >> 6, lane = tid & 63, ln = lane & 15, q = lane >> 4;

    // h0 = 0 (both buffers, padding included — belt and suspenders)
    for (int i = tid; i < 2 * 16 * HPAD; i += 1024)
        ((__hip_bfloat16*)hbuf)[i] = __float2bfloat16(0.0f);
    // gather xe for t=0: wave w owns batch row w; 8B per lane
    {
        int row = tid >> 6, col = (tid & 63) * 4;
        int tok = get_tok(x, (b0 + row) * T_STEPS + 0, x64);
        *(uint2*)(&xe_s[row][col]) = *(const uint2*)(emb + (size_t)tok * EMB + col);
    }
    __syncthreads();

    const int n0 = w * 32 + ln;                     // wave owns cols n0, n0+16
    const float bias0 = __bfloat162float(Wb[n0])      + __bfloat162float(Ub[n0]);
    const float bias1 = __bfloat162float(Wb[n0 + 16]) + __bfloat162float(Ub[n0 + 16]);
    // B-operand (row-major W, B[k][n] = W[n][k]): contiguous 16B per lane
    const __hip_bfloat16* ww0 = Ww + (size_t)n0 * EMB + q * 8;
    const __hip_bfloat16* ww1 = ww0 + 16 * EMB;
    const __hip_bfloat16* uw0 = Uw + (size_t)n0 * HID + q * 8;
    const __hip_bfloat16* uw1 = uw0 + 16 * HID;

    for (int t = 0; t < T_STEPS; ++t) {
        f32x4 acc0, acc1;
#pragma unroll
        for (int r = 0; r < 4; ++r) { acc0[r] = bias0; acc1[r] = bias1; }

        // wx: [16 x 256] @ Ww^T     A[m=ln][k=q*8+j] per 32-K block
#pragma unroll
        for (int kt = 0; kt < 8; ++kt) {
            bf16x8 a   = *(const bf16x8*)(&xe_s[ln][kt * 32 + q * 8]);
            bf16x8 bw0 = *(const bf16x8*)(ww0 + kt * 32);
            bf16x8 bw1 = *(const bf16x8*)(ww1 + kt * 32);
            acc0 = __builtin_amdgcn_mfma_f32_16x16x32_bf16(a, bw0, acc0, 0, 0, 0);
            acc1 = __builtin_amdgcn_mfma_f32_16x16x32_bf16(a, bw1, acc1, 0, 0, 0);
        }
        // recurrent: [16 x 512] @ Uw^T
        const __hip_bfloat16 (*hr)[HPAD] = hbuf[t & 1];
#pragma unroll
        for (int kt = 0; kt < 16; ++kt) {
            bf16x8 a   = *(const bf16x8*)(&hr[ln][kt * 32 + q * 8]);
            bf16x8 bu0 = *(const bf16x8*)(uw0 + kt * 32);
            bf16x8 bu1 = *(const bf16x8*)(uw1 + kt * 32);
            acc0 = __builtin_amdgcn_mfma_f32_16x16x32_bf16(a, bu0, acc0, 0, 0, 0);
            acc1 = __builtin_amdgcn_mfma_f32_16x16x32_bf16(a, bu1, acc1, 0, 0, 0);
        }
        __syncthreads();   // all reads of xe_s / hbuf[t&1] done

        // write h_{t+1}: C/D layout row=q*4+r (batch), col=n (hidden)
        __hip_bfloat16 (*hw)[HPAD] = hbuf[(t + 1) & 1];
#pragma unroll
        for (int r = 0; r < 4; ++r) {
            hw[q * 4 + r][n0]      = __float2bfloat16(tanhf(acc0[r]));
            hw[q * 4 + r][n0 + 16] = __float2bfloat16(tanhf(acc1[r]));
        }
        // gather xe for t+1 (overwrites xe_s; reads were barrier-protected)
        if (t + 1 < T_STEPS) {
            int row = tid >> 6, col = (tid & 63) * 4;
            int tok = get_tok(x, (b0 + row) * T_STEPS + (t + 1), x64);
            *(uint2*)(&xe_s[row][col]) = *(const uint2*)(emb + (size_t)tok * EMB + col);
        }
        __syncthreads();   // h / xe ready for next step
    }

    // logits = hT @ Vw^T + Vb ; final h in hbuf[0] (T even)
    if (tid < 512) {
        int lb = tid >> 5, rem = tid & 31, o = rem >> 4, kp = rem & 15;
        float s = 0.0f;
#pragma unroll 4
        for (int j = 0; j < 32; ++j) {
            int k = kp * 32 + j;
            s += __bfloat162float(hbuf[0][lb][k]) * __bfloat162float(Vw[o * HID + k]);
        }
        s += __shfl_xor(s, 1);
        s += __shfl_xor(s, 2);
        s += __shfl_xor(s, 4);
        s += __shfl_xor(s, 8);
        if (kp == 0)
            stf(outv, (b0 + lb) * 2 + o, s + __bfloat162float(Vb[o]), false);
    }
}

// ---------------- fixup: NaN-check + anchor recompute (proven r3 math) ------
#define B_PER 2
__global__ __launch_bounds__(512) void fixup(
    const int* __restrict__ x, const void* __restrict__ emb,
    const void* __restrict__ Ww, const void* __restrict__ Wb,
    const void* __restrict__ Uw, const void* __restrict__ Ub,
    const void* __restrict__ Vw, const void* __restrict__ Vb,
    void* __restrict__ out)
{
    __shared__ float h_s[2][B_PER][HID];
    __shared__ float xe_s[B_PER][EMB];
    __shared__ int   flags_s, bad_s;

    const int tid = threadIdx.x;
    const int b0  = blockIdx.x * B_PER;

    if (tid == 0) {
        int fl = detect_flags(x, emb);
        flags_s = fl;
        bool f32o = (fl & 1) != 0;   // out dtype follows float dtype
        int bad = 0;
        for (int i = 0; i < 2 * B_PER; ++i) {
            int oi = b0 * 2 + i;
            if (f32o) {
                float v = ((const float*)out)[oi];
                bad |= (v != v);
            } else {
                unsigned short u = ((const unsigned short*)out)[oi];
                bad |= (((u & 0x7F80u) == 0x7F80u) && ((u & 0x7Fu) != 0));
            }
        }
        bad_s = bad;
    }
    __syncthreads();
    if (!bad_s) return;                      // fast path was clean (uniform)

    const bool f32w = (flags_s & 1) != 0;
    const bool x64  = (flags_s & 2) != 0;
    const int n = tid;
    const float bias = ldf(Wb, n, f32w) + ldf(Ub, n, f32w);

    for (int b = 0; b < B_PER; ++b) h_s[0][b][n] = 0.0f;

    for (int t = 0; t < T_STEPS; ++t) {
        {
            int b = tid >> 8, c = tid & 255;
            int tok = get_tok(x, (b0 + b) * T_STEPS + t, x64);
            xe_s[b][c] = ldf(emb, (long)tok * EMB + c, f32w);
        }
        __syncthreads();

        float acc0 = bias, acc1 = bias;
        const long wrow = (long)n * EMB;
#pragma unroll 8
        for (int k = 0; k < EMB; ++k) {
            float wv = ldf(Ww, wrow + k, f32w);
            acc0 += xe_s[0][k] * wv;
            acc1 += xe_s[1][k] * wv;
        }
        const long urow = (long)n * HID;
        const float* hc0 = h_s[t & 1][0];
        const float* hc1 = h_s[t & 1][1];
#pragma unroll 8
        for (int k = 0; k < HID; ++k) {
            float uv = ldf(Uw, urow + k, f32w);
            acc0 += hc0[k] * uv;
            acc1 += hc1[k] * uv;
        }
        h_s[(t + 1) & 1][0][n] = tanhf(acc0);
        h_s[(t + 1) & 1][1][n] = tanhf(acc1);
        __syncthreads();
    }

    if (tid < 2 * B_PER) {
        int b = tid >> 1, o = tid & 1;
        float s = ldf(Vb, o, f32w);
        for (int k = 0; k < HID; ++k)
            s += h_s[0][b][k] * ldf(Vw, (long)o * HID + k, f32w);
        stf(out, (b0 + b) * 2 + o, s, f32w);
    }
}

extern "C" void kernel_launch(void* const* d_in, const int* in_sizes, int n_in,
                              void* d_out, int out_size, void* d_ws, size_t ws_size,
                              hipStream_t stream) {
    const int* x = (const int*)d_in[0];
    scan_mfma<<<8, 1024, 0, stream>>>(
        x, d_in[1], d_in[2], d_in[3], d_in[4], d_in[5], d_in[6], d_in[7], d_out);
    fixup<<<64, 512, 0, stream>>>(
        x, d_in[1], d_in[2], d_in[3], d_in[4], d_in[5], d_in[6], d_in[7], d_out);
}

// Round 5
// 7052.510 us; speedup vs baseline: 12.3813x; 12.3678x over previous
//
#include <hip/hip_runtime.h>
#include <hip/hip_bf16.h>
#include <math.h>

// Elman RNN. VOCAB=50257, EMB=256, HID=512, OUT=2, B=128, T=512.
// R5: world is f32-in-memory (established R4 post-mortem). prep converts
// weights to packed bf16 in d_ws; MFMA scan streams them coalesced from L2;
// fixup = NaN safety net + forced-anchor fallback when ws is too small.

#define VOCAB   50257
#define T_STEPS 512
#define HID     512
#define EMB     256
#define XPAD    264
#define HPAD    528

// ws layout (byte offsets)
#define WS_UWP  0          // 262144 bf16 (512 KB) packed Uw fragments
#define WS_WWP  524288     // 131072 bf16 (256 KB) packed Ww fragments
#define WS_BIAS 786432     // 512 f32 : Wb+Ub
#define WS_VW   788480     // 1024 bf16 : Vw
#define WS_NEED 790528

typedef __bf16 bf16x8 __attribute__((ext_vector_type(8)));
typedef float  f32x4  __attribute__((ext_vector_type(4)));

__device__ inline float ldf(const void* p, long i, bool f32) {
    if (f32) return ((const float*)p)[i];
    unsigned bits = ((unsigned)((const unsigned short*)p)[i]) << 16;
    return __uint_as_float(bits);
}
__device__ inline void stf(void* p, int i, float v, bool f32) {
    if (f32) { ((float*)p)[i] = v; return; }
    unsigned b = __float_as_uint(v);
    unsigned r = (b + 0x7fffu + ((b >> 16) & 1u)) >> 16;   // RNE bf16
    ((unsigned short*)p)[i] = (unsigned short)r;
}
__device__ inline int get_tok(const int* x, int idx, bool x64) {
    unsigned u = (unsigned)(x64 ? x[2 * idx] : x[idx]);
    return (u < (unsigned)VOCAB) ? (int)u : 0;
}
// dtype probes: constant across calls -> graph-safe
__device__ inline int detect_flags(const int* x, const void* emb) {
    int allz = 1;   // f32 floats? emb row0 (f32) = uint16 words [0,512) all zero
    const unsigned short* e16 = (const unsigned short*)emb;
    for (int i = 256; i < 320; ++i) allz &= (e16[i] == 0);
    int x64 = 1;    // int64 x? odd int32 words all zero
    for (int j = 1; j < 16; j += 2) x64 &= (x[j] == 0);
    return allz | (x64 << 1);
}

// ---------------- prep: build packed bf16 weights in ws ---------------------
// UwP group g = ((p*16+kt)*2+half)*64+lane holds 8 bf16:
//   Uw[row = p*32 + (lane&15) + half*16][k = kt*32 + (lane>>4)*8 + j]
// WwP identical with kt<8, EMB row stride.
__global__ __launch_bounds__(256) void prep(
    const int* __restrict__ x, const void* __restrict__ emb,
    const void* __restrict__ Ww, const void* __restrict__ Wb,
    const void* __restrict__ Uw, const void* __restrict__ Ub,
    const void* __restrict__ Vw, unsigned char* __restrict__ ws)
{
    __shared__ int flags_s;
    if (threadIdx.x == 0) flags_s = detect_flags(x, emb);
    __syncthreads();
    const bool f32w = (flags_s & 1) != 0;

    __hip_bfloat16* UwP   = (__hip_bfloat16*)(ws + WS_UWP);
    __hip_bfloat16* WwP   = (__hip_bfloat16*)(ws + WS_WWP);
    float*          biasf = (float*)(ws + WS_BIAS);
    __hip_bfloat16* VwB   = (__hip_bfloat16*)(ws + WS_VW);

    const int total = 32768 + 16384 + 512 + 1024;
    const int nthr  = gridDim.x * blockDim.x;
    for (int gid = blockIdx.x * blockDim.x + threadIdx.x; gid < total; gid += nthr) {
        if (gid < 32768) {
            int g = gid, lane = g & 63, rest = g >> 6;
            int half = rest & 1, ktp = rest >> 1, kt = ktp & 15, p = ktp >> 4;
            int row = p * 32 + (lane & 15) + half * 16;
            int kb  = kt * 32 + (lane >> 4) * 8;
#pragma unroll
            for (int j = 0; j < 8; ++j)
                UwP[(size_t)g * 8 + j] =
                    __float2bfloat16(ldf(Uw, (long)row * HID + kb + j, f32w));
        } else if (gid < 32768 + 16384) {
            int g = gid - 32768, lane = g & 63, rest = g >> 6;
            int half = rest & 1, ktp = rest >> 1, kt = ktp & 7, p = ktp >> 3;
            int row = p * 32 + (lane & 15) + half * 16;
            int kb  = kt * 32 + (lane >> 4) * 8;
#pragma unroll
            for (int j = 0; j < 8; ++j)
                WwP[(size_t)g * 8 + j] =
                    __float2bfloat16(ldf(Ww, (long)row * EMB + kb + j, f32w));
        } else if (gid < 32768 + 16384 + 512) {
            int n = gid - (32768 + 16384);
            biasf[n] = ldf(Wb, n, f32w) + ldf(Ub, n, f32w);
        } else {
            int i = gid - (32768 + 16384 + 512);
            VwB[i] = __float2bfloat16(ldf(Vw, i, f32w));
        }
    }
}

// ---------------- fused MFMA scan (reads packed bf16 ws weights) ------------
__global__ __launch_bounds__(1024, 4) void scan_mfma(
    const int* __restrict__ x, const void* __restrict__ embv,
    const unsigned char* __restrict__ ws, const void* __restrict__ Vbv,
    void* __restrict__ outv)
{
    __shared__ __align__(16) __hip_bfloat16 xe_s[16][XPAD];
    __shared__ __align__(16) __hip_bfloat16 hbuf[2][16][HPAD];
    __shared__ int flags_s;

    const int tid = threadIdx.x, b0 = blockIdx.x * 16;
    if (tid == 0) flags_s = detect_flags(x, embv);
    __syncthreads();
    const bool f32w = (flags_s & 1) != 0;
    const bool x64  = (flags_s & 2) != 0;

    const __hip_bfloat16* UwP   = (const __hip_bfloat16*)(ws + WS_UWP);
    const __hip_bfloat16* WwP   = (const __hip_bfloat16*)(ws + WS_WWP);
    const float*          biasf = (const float*)(ws + WS_BIAS);
    const __hip_bfloat16* VwB   = (const __hip_bfloat16*)(ws + WS_VW);

    const int w = tid >> 6, lane = tid & 63, ln = lane & 15, q = lane >> 4;

    for (int i = tid; i < 2 * 16 * HPAD; i += 1024)
        ((__hip_bfloat16*)hbuf)[i] = __float2bfloat16(0.0f);

    // xe gather t=0: wave w -> batch row w; lane covers cols [lane*4, lane*4+4)
    {
        int tok = get_tok(x, (b0 + w) * T_STEPS + 0, x64);
        int col = lane * 4;
        float v0, v1, v2, v3;
        if (f32w) {
            const float* e = (const float*)embv + (size_t)tok * EMB + col;
            v0 = e[0]; v1 = e[1]; v2 = e[2]; v3 = e[3];
        } else {
            const unsigned short* e = (const unsigned short*)embv + (size_t)tok * EMB + col;
            v0 = __uint_as_float((unsigned)e[0] << 16);
            v1 = __uint_as_float((unsigned)e[1] << 16);
            v2 = __uint_as_float((unsigned)e[2] << 16);
            v3 = __uint_as_float((unsigned)e[3] << 16);
        }
        xe_s[w][col]     = __float2bfloat16(v0);
        xe_s[w][col + 1] = __float2bfloat16(v1);
        xe_s[w][col + 2] = __float2bfloat16(v2);
        xe_s[w][col + 3] = __float2bfloat16(v3);
    }
    __syncthreads();

    const int n0 = w * 32 + ln;
    const float bias0 = biasf[n0], bias1 = biasf[n0 + 16];
    // packed fragment bases: + (kt*2+half)*512 per step of the kt loops
    const __hip_bfloat16* uwb = UwP + (size_t)w * 16384 + lane * 8;
    const __hip_bfloat16* wwb = WwP + (size_t)w * 8192  + lane * 8;

    for (int t = 0; t < T_STEPS; ++t) {
        // early-issue next xe load (global, independent of MFMA phase)
        float nv0 = 0, nv1 = 0, nv2 = 0, nv3 = 0;
        const bool have_next = (t + 1 < T_STEPS);
        if (have_next) {
            int tok = get_tok(x, (b0 + w) * T_STEPS + t + 1, x64);
            int col = lane * 4;
            if (f32w) {
                const float* e = (const float*)embv + (size_t)tok * EMB + col;
                nv0 = e[0]; nv1 = e[1]; nv2 = e[2]; nv3 = e[3];
            } else {
                const unsigned short* e = (const unsigned short*)embv + (size_t)tok * EMB + col;
                nv0 = __uint_as_float((unsigned)e[0] << 16);
                nv1 = __uint_as_float((unsigned)e[1] << 16);
                nv2 = __uint_as_float((unsigned)e[2] << 16);
                nv3 = __uint_as_float((unsigned)e[3] << 16);
            }
        }

        f32x4 acc0, acc1;
#pragma unroll
        for (int r = 0; r < 4; ++r) { acc0[r] = bias0; acc1[r] = bias1; }

        // wx phase: [16 x 256] @ Ww^T
#pragma unroll
        for (int kt = 0; kt < 8; ++kt) {
            bf16x8 a  = *(const bf16x8*)(&xe_s[ln][kt * 32 + q * 8]);
            bf16x8 b0f = *(const bf16x8*)(wwb + (kt * 2 + 0) * 512);
            bf16x8 b1f = *(const bf16x8*)(wwb + (kt * 2 + 1) * 512);
            acc0 = __builtin_amdgcn_mfma_f32_16x16x32_bf16(a, b0f, acc0, 0, 0, 0);
            acc1 = __builtin_amdgcn_mfma_f32_16x16x32_bf16(a, b1f, acc1, 0, 0, 0);
        }
        // recurrent phase: [16 x 512] @ Uw^T
        const __hip_bfloat16 (*hr)[HPAD] = hbuf[t & 1];
#pragma unroll
        for (int kt = 0; kt < 16; ++kt) {
            bf16x8 a  = *(const bf16x8*)(&hr[ln][kt * 32 + q * 8]);
            bf16x8 bu0 = *(const bf16x8*)(uwb + (kt * 2 + 0) * 512);
            bf16x8 bu1 = *(const bf16x8*)(uwb + (kt * 2 + 1) * 512);
            acc0 = __builtin_amdgcn_mfma_f32_16x16x32_bf16(a, bu0, acc0, 0, 0, 0);
            acc1 = __builtin_amdgcn_mfma_f32_16x16x32_bf16(a, bu1, acc1, 0, 0, 0);
        }
        __syncthreads();   // all reads of xe_s / hbuf[t&1] complete

        // write h_{t+1}: C/D layout row=q*4+r (batch), col=n
        __hip_bfloat16 (*hw)[HPAD] = hbuf[(t + 1) & 1];
#pragma unroll
        for (int r = 0; r < 4; ++r) {
            hw[q * 4 + r][n0]      = __float2bfloat16(tanhf(acc0[r]));
            hw[q * 4 + r][n0 + 16] = __float2bfloat16(tanhf(acc1[r]));
        }
        if (have_next) {
            int col = lane * 4;
            xe_s[w][col]     = __float2bfloat16(nv0);
            xe_s[w][col + 1] = __float2bfloat16(nv1);
            xe_s[w][col + 2] = __float2bfloat16(nv2);
            xe_s[w][col + 3] = __float2bfloat16(nv3);
        }
        __syncthreads();   // h / xe sealed for next step
    }

    // logits = hT @ Vw^T + Vb ; final h in hbuf[0] (T even)
    if (tid < 512) {
        int lb = tid >> 5, rem = tid & 31, o = rem >> 4, kp = rem & 15;
        float s = 0.0f;
#pragma unroll 4
        for (int j = 0; j < 32; ++j) {
            int k = kp * 32 + j;
            s += __bfloat162float(hbuf[0][lb][k]) * __bfloat162float(VwB[o * HID + k]);
        }
        s += __shfl_xor(s, 1);
        s += __shfl_xor(s, 2);
        s += __shfl_xor(s, 4);
        s += __shfl_xor(s, 8);
        if (kp == 0)
            stf(outv, (b0 + lb) * 2 + o, s + ldf(Vbv, o, f32w), f32w);
    }
}

// ---------------- fixup: NaN net + forced-anchor fallback -------------------
#define B_PER 2
__global__ __launch_bounds__(512) void fixup(
    const int* __restrict__ x, const void* __restrict__ emb,
    const void* __restrict__ Ww, const void* __restrict__ Wb,
    const void* __restrict__ Uw, const void* __restrict__ Ub,
    const void* __restrict__ Vw, const void* __restrict__ Vb,
    void* __restrict__ out, int force)
{
    __shared__ float h_s[2][B_PER][HID];
    __shared__ float xe_s[B_PER][EMB];
    __shared__ int   flags_s, bad_s;

    const int tid = threadIdx.x;
    const int b0  = blockIdx.x * B_PER;

    if (tid == 0) {
        int fl = detect_flags(x, emb);
        flags_s = fl;
        int bad = force;
        if (!force) {
            bool f32o = (fl & 1) != 0;
            for (int i = 0; i < 2 * B_PER; ++i) {
                int oi = b0 * 2 + i;
                if (f32o) {
                    float v = ((const float*)out)[oi];
                    bad |= (v != v);
                } else {
                    unsigned short u = ((const unsigned short*)out)[oi];
                    bad |= (((u & 0x7F80u) == 0x7F80u) && ((u & 0x7Fu) != 0));
                }
            }
        }
        bad_s = bad;
    }
    __syncthreads();
    if (!bad_s) return;

    const bool f32w = (flags_s & 1) != 0;
    const bool x64  = (flags_s & 2) != 0;
    const int n = tid;
    const float bias = ldf(Wb, n, f32w) + ldf(Ub, n, f32w);

    for (int b = 0; b < B_PER; ++b) h_s[0][b][n] = 0.0f;

    for (int t = 0; t < T_STEPS; ++t) {
        {
            int b = tid >> 8, c = tid & 255;
            int tok = get_tok(x, (b0 + b) * T_STEPS + t, x64);
            xe_s[b][c] = ldf(emb, (long)tok * EMB + c, f32w);
        }
        __syncthreads();

        float acc0 = bias, acc1 = bias;
        const long wrow = (long)n * EMB;
#pragma unroll 8
        for (int k = 0; k < EMB; ++k) {
            float wv = ldf(Ww, wrow + k, f32w);
            acc0 += xe_s[0][k] * wv;
            acc1 += xe_s[1][k] * wv;
        }
        const long urow = (long)n * HID;
        const float* hc0 = h_s[t & 1][0];
        const float* hc1 = h_s[t & 1][1];
#pragma unroll 8
        for (int k = 0; k < HID; ++k) {
            float uv = ldf(Uw, urow + k, f32w);
            acc0 += hc0[k] * uv;
            acc1 += hc1[k] * uv;
        }
        h_s[(t + 1) & 1][0][n] = tanhf(acc0);
        h_s[(t + 1) & 1][1][n] = tanhf(acc1);
        __syncthreads();
    }

    if (tid < 2 * B_PER) {
        int b = tid >> 1, o = tid & 1;
        float s = ldf(Vb, o, f32w);
        for (int k = 0; k < HID; ++k)
            s += h_s[0][b][k] * ldf(Vw, (long)o * HID + k, f32w);
        stf(out, (b0 + b) * 2 + o, s, f32w);
    }
}

extern "C" void kernel_launch(void* const* d_in, const int* in_sizes, int n_in,
                              void* d_out, int out_size, void* d_ws, size_t ws_size,
                              hipStream_t stream) {
    const int* x = (const int*)d_in[0];
    const int force = (ws_size < (size_t)WS_NEED) ? 1 : 0;   // constant per session
    if (!force) {
        prep<<<128, 256, 0, stream>>>(
            x, d_in[1], d_in[2], d_in[3], d_in[4], d_in[5], d_in[6],
            (unsigned char*)d_ws);
        scan_mfma<<<8, 1024, 0, stream>>>(
            x, d_in[1], (const unsigned char*)d_ws, d_in[7], d_out);
    }
    fixup<<<64, 512, 0, stream>>>(
        x, d_in[1], d_in[2], d_in[3], d_in[4], d_in[5], d_in[6], d_in[7],
        d_out, force);
}

// Round 6
// 4535.335 us; speedup vs baseline: 19.2532x; 1.5550x over previous
//
#include <hip/hip_runtime.h>
#include <hip/hip_bf16.h>
#include <math.h>

// Elman RNN. VOCAB=50257, EMB=256, HID=512, OUT=2, B=128, T=512.
// R6: register-resident weights. 32 blocks x 256 thr = 8 batch-groups x 4
// column-blocks. Each wave owns 32 output columns; its Uw (128 VGPR) and Ww
// (64 VGPR) fragments live in registers for the entire 512-step scan (r5's
// counters showed VGPR=64 forced L2 re-streaming of 768 KB/step = the 7 ms).
// Per step the 4 blocks of a group exchange h through global memory with a
// device-scope monotonic-counter barrier (all 32 blocks co-resident).

#define VOCAB   50257
#define T_STEPS 512
#define HID     512
#define EMB     256
#define XPAD    264
#define HPAD    528
#define BPG     4                 // blocks per batch-group
#define WS_H    4096              // [2][128][512] ushort = 256 KB
#define WS_NEED (4096 + 2 * 128 * 512 * 2)

typedef __bf16 bf16x8 __attribute__((ext_vector_type(8)));
typedef float  f32x4  __attribute__((ext_vector_type(4)));

__device__ inline float ldf(const void* p, long i, bool f32) {
    if (f32) return ((const float*)p)[i];
    unsigned bits = ((unsigned)((const unsigned short*)p)[i]) << 16;
    return __uint_as_float(bits);
}
__device__ inline void stf(void* p, long i, float v, bool f32) {
    if (f32) { ((float*)p)[i] = v; return; }
    unsigned b = __float_as_uint(v);
    unsigned r = (b + 0x7fffu + ((b >> 16) & 1u)) >> 16;   // RNE bf16
    ((unsigned short*)p)[i] = (unsigned short)r;
}
__device__ inline int get_tok(const int* x, int idx, bool x64) {
    unsigned u = (unsigned)(x64 ? x[2 * idx] : x[idx]);
    return (u < (unsigned)VOCAB) ? (int)u : 0;
}
__device__ inline int detect_flags(const int* x, const void* emb) {
    int allz = 1;   // floats f32?  (bf16-view of f32 emb row0 stays zero)
    const unsigned short* e16 = (const unsigned short*)emb;
    for (int i = 256; i < 320; ++i) allz &= (e16[i] == 0);
    int x64 = 1;    // x int64?
    for (int j = 1; j < 16; j += 2) x64 &= (x[j] == 0);
    return allz | (x64 << 1);
}
// 16 consecutive embedding values -> two bf16x8
__device__ inline void load_xe(const void* emb, long base, bool f32,
                               bf16x8* a, bf16x8* b) {
    if (f32) {
        const float* p = (const float*)emb + base;
        bf16x8 va, vb;
#pragma unroll
        for (int j = 0; j < 8; ++j) va[j] = (__bf16)p[j];
#pragma unroll
        for (int j = 0; j < 8; ++j) vb[j] = (__bf16)p[8 + j];
        *a = va; *b = vb;
    } else {
        const bf16x8* p = (const bf16x8*)((const unsigned short*)emb + base);
        *a = p[0]; *b = p[1];
    }
}

// ---------------- register-resident MFMA scan -------------------------------
__global__ __launch_bounds__(256, 1) void scan_mfma(
    const int* __restrict__ x, const void* __restrict__ embv,
    const void* __restrict__ Wwv, const void* __restrict__ Wbv,
    const void* __restrict__ Uwv, const void* __restrict__ Ubv,
    const void* __restrict__ Vwv, const void* __restrict__ Vbv,
    unsigned char* __restrict__ ws, void* __restrict__ outv)
{
    __shared__ __align__(16) __hip_bfloat16 xe_s[16][XPAD];       // 8.4 KB
    __shared__ __align__(16) __hip_bfloat16 hbuf[2][16][HPAD];    // 33.8 KB
    __shared__ int flags_s;

    const int tid = threadIdx.x;
    const int g   = blockIdx.x >> 2;       // batch group (8)
    const int cg  = blockIdx.x & 3;        // column group (4)
    const int b0  = g * 16;

    if (tid == 0) flags_s = detect_flags(x, embv);
    __syncthreads();
    const bool f32w = (flags_s & 1) != 0;
    const bool x64  = (flags_s & 2) != 0;

    const int w = tid >> 6, lane = tid & 63, ln = lane & 15, q = lane >> 4;
    const int n0 = cg * 128 + w * 32 + ln;          // wave's cols: n0, n0+16

    for (int i = tid; i < 2 * 16 * HPAD; i += 256)
        ((__hip_bfloat16*)hbuf)[i] = __float2bfloat16(0.0f);

    // ---- one-time weight fragment loads (stay in VGPRs for all 512 steps) --
    // B[k=kt*32+q*8+j][n] = W[n][k], n = n0 + half*16
    bf16x8 ufr[2][16], wfr[2][8];
#pragma unroll
    for (int half = 0; half < 2; ++half) {
        const long n = n0 + half * 16;
#pragma unroll
        for (int kt = 0; kt < 16; ++kt) {
            bf16x8 v;
#pragma unroll
            for (int j = 0; j < 8; ++j)
                v[j] = (__bf16)ldf(Uwv, n * HID + kt * 32 + q * 8 + j, f32w);
            ufr[half][kt] = v;
        }
#pragma unroll
        for (int kt = 0; kt < 8; ++kt) {
            bf16x8 v;
#pragma unroll
            for (int j = 0; j < 8; ++j)
                v[j] = (__bf16)ldf(Wwv, n * EMB + kt * 32 + q * 8 + j, f32w);
            wfr[half][kt] = v;
        }
    }
    const float bias0 = ldf(Wbv, n0, f32w)      + ldf(Ubv, n0, f32w);
    const float bias1 = ldf(Wbv, n0 + 16, f32w) + ldf(Ubv, n0 + 16, f32w);

    // xe staging map: thread -> row xr (16 rows), 16 cols at xc
    const int xr = tid >> 4, xc = (tid & 15) * 16;
    {
        int tok = get_tok(x, (b0 + xr) * T_STEPS + 0, x64);
        bf16x8 xa, xb;
        load_xe(embv, (long)tok * EMB + xc, f32w, &xa, &xb);
        *(bf16x8*)&xe_s[xr][xc]     = xa;
        *(bf16x8*)&xe_s[xr][xc + 8] = xb;
    }
    __syncthreads();

    unsigned short* hg  = (unsigned short*)(ws + WS_H);
    int*            cnt = (int*)(void*)ws + g * 32;    // 128 B apart per group

    for (int t = 0; t < T_STEPS; ++t) {
        // prefetch xe(t+1) into regs (consumed after the MFMA phase)
        bf16x8 nxa, nxb;
        const bool have_next = (t + 1 < T_STEPS);
        if (have_next) {
            int tok = get_tok(x, (b0 + xr) * T_STEPS + (t + 1), x64);
            load_xe(embv, (long)tok * EMB + xc, f32w, &nxa, &nxb);
        }

        f32x4 acc0, acc1;
#pragma unroll
        for (int r = 0; r < 4; ++r) { acc0[r] = bias0; acc1[r] = bias1; }

        // wx phase: [16 x 256] @ Ww^T (A from xe_s)
#pragma unroll
        for (int kt = 0; kt < 8; ++kt) {
            bf16x8 a = *(const bf16x8*)&xe_s[ln][kt * 32 + q * 8];
            acc0 = __builtin_amdgcn_mfma_f32_16x16x32_bf16(a, wfr[0][kt], acc0, 0, 0, 0);
            acc1 = __builtin_amdgcn_mfma_f32_16x16x32_bf16(a, wfr[1][kt], acc1, 0, 0, 0);
        }
        // recurrent phase: [16 x 512] @ Uw^T (A from hbuf[t&1])
        const __hip_bfloat16 (*hr)[HPAD] = hbuf[t & 1];
#pragma unroll
        for (int kt = 0; kt < 16; ++kt) {
            bf16x8 a = *(const bf16x8*)&hr[ln][kt * 32 + q * 8];
            acc0 = __builtin_amdgcn_mfma_f32_16x16x32_bf16(a, ufr[0][kt], acc0, 0, 0, 0);
            acc1 = __builtin_amdgcn_mfma_f32_16x16x32_bf16(a, ufr[1][kt], acc1, 0, 0, 0);
        }
        __syncthreads();                    // xe_s reads complete

        if (have_next) {                    // stage xe(t+1)
            *(bf16x8*)&xe_s[xr][xc]     = nxa;
            *(bf16x8*)&xe_s[xr][xc + 8] = nxb;
        }

        // tanh + publish own 32-col slice of h_{t+1} (C/D: batch=q*4+r, col=n)
        const int nb = (t + 1) & 1;
        unsigned short* hb = hg + nb * (128 * 512) + b0 * 512;
#pragma unroll
        for (int r = 0; r < 4; ++r) {
            stf(hb, (long)(q * 4 + r) * 512 + n0,      tanhf(acc0[r]), false);
            stf(hb, (long)(q * 4 + r) * 512 + n0 + 16, tanhf(acc1[r]), false);
        }
        __threadfence();                    // release h writes (device scope)
        __syncthreads();
        if (tid == 0) {
            atomicAdd(cnt, 1);
            const int target = BPG * (t + 1);
            while (__hip_atomic_load(cnt, __ATOMIC_RELAXED,
                                     __HIP_MEMORY_SCOPE_AGENT) < target)
                __builtin_amdgcn_s_sleep(1);
        }
        __syncthreads();
        __threadfence();                    // acquire before reading peers' h

        // copy full h_{t+1} (16 rows x 512) global -> LDS hbuf[nb]
        {
            const uint4* src = (const uint4*)(hg + nb * (128 * 512) + b0 * 512);
#pragma unroll
            for (int i = tid; i < 1024; i += 256) {
                int row = i >> 6, c8 = (i & 63) * 8;
                uint4 v = src[i];
                *(uint4*)&hbuf[nb][row][c8] = v;
            }
        }
        __syncthreads();
    }

    // logits = hT @ Vw^T + Vb ; full h_T is in hbuf[0] (T even); cg0 writes
    if (cg == 0) {
        int b = tid >> 4, rem = tid & 15, o = rem >> 3, kp = rem & 7;
        float s = 0.0f;
#pragma unroll 4
        for (int j = 0; j < 64; ++j) {
            int k = kp * 64 + j;
            s += __bfloat162float(hbuf[0][b][k]) * ldf(Vwv, (long)o * HID + k, f32w);
        }
        s += __shfl_xor(s, 1);
        s += __shfl_xor(s, 2);
        s += __shfl_xor(s, 4);
        if (kp == 0)
            stf(outv, (long)(b0 + b) * 2 + o, s + ldf(Vbv, o, f32w), f32w);
    }
}

// ---------------- fixup: NaN net + forced-anchor fallback -------------------
#define B_PER 2
__global__ __launch_bounds__(512) void fixup(
    const int* __restrict__ x, const void* __restrict__ emb,
    const void* __restrict__ Ww, const void* __restrict__ Wb,
    const void* __restrict__ Uw, const void* __restrict__ Ub,
    const void* __restrict__ Vw, const void* __restrict__ Vb,
    void* __restrict__ out, int force)
{
    __shared__ float h_s[2][B_PER][HID];
    __shared__ float xe_s[B_PER][EMB];
    __shared__ int   flags_s, bad_s;

    const int tid = threadIdx.x;
    const int b0  = blockIdx.x * B_PER;

    if (tid == 0) {
        int fl = detect_flags(x, emb);
        flags_s = fl;
        int bad = force;
        if (!force) {
            bool f32o = (fl & 1) != 0;
            for (int i = 0; i < 2 * B_PER; ++i) {
                int oi = b0 * 2 + i;
                if (f32o) {
                    float v = ((const float*)out)[oi];
                    bad |= (v != v);
                } else {
                    unsigned short u = ((const unsigned short*)out)[oi];
                    bad |= (((u & 0x7F80u) == 0x7F80u) && ((u & 0x7Fu) != 0));
                }
            }
        }
        bad_s = bad;
    }
    __syncthreads();
    if (!bad_s) return;

    const bool f32w = (flags_s & 1) != 0;
    const bool x64  = (flags_s & 2) != 0;
    const int n = tid;
    const float bias = ldf(Wb, n, f32w) + ldf(Ub, n, f32w);

    for (int b = 0; b < B_PER; ++b) h_s[0][b][n] = 0.0f;

    for (int t = 0; t < T_STEPS; ++t) {
        {
            int b = tid >> 8, c = tid & 255;
            int tok = get_tok(x, (b0 + b) * T_STEPS + t, x64);
            xe_s[b][c] = ldf(emb, (long)tok * EMB + c, f32w);
        }
        __syncthreads();

        float acc0 = bias, acc1 = bias;
        const long wrow = (long)n * EMB;
#pragma unroll 8
        for (int k = 0; k < EMB; ++k) {
            float wv = ldf(Ww, wrow + k, f32w);
            acc0 += xe_s[0][k] * wv;
            acc1 += xe_s[1][k] * wv;
        }
        const long urow = (long)n * HID;
        const float* hc0 = h_s[t & 1][0];
        const float* hc1 = h_s[t & 1][1];
#pragma unroll 8
        for (int k = 0; k < HID; ++k) {
            float uv = ldf(Uw, urow + k, f32w);
            acc0 += hc0[k] * uv;
            acc1 += hc1[k] * uv;
        }
        h_s[(t + 1) & 1][0][n] = tanhf(acc0);
        h_s[(t + 1) & 1][1][n] = tanhf(acc1);
        __syncthreads();
    }

    if (tid < 2 * B_PER) {
        int b = tid >> 1, o = tid & 1;
        float s = ldf(Vb, o, f32w);
        for (int k = 0; k < HID; ++k)
            s += h_s[0][b][k] * ldf(Vw, (long)o * HID + k, f32w);
        stf(out, (b0 + b) * 2 + o, s, f32w);
    }
}

extern "C" void kernel_launch(void* const* d_in, const int* in_sizes, int n_in,
                              void* d_out, int out_size, void* d_ws, size_t ws_size,
                              hipStream_t stream) {
    const int* x = (const int*)d_in[0];
    const int force = (ws_size < (size_t)WS_NEED) ? 1 : 0;
    if (!force) {
        hipMemsetAsync(d_ws, 0, 4096, stream);       // zero barrier counters
        scan_mfma<<<32, 256, 0, stream>>>(
            x, d_in[1], d_in[2], d_in[3], d_in[4], d_in[5], d_in[6], d_in[7],
            (unsigned char*)d_ws, d_out);
    }
    fixup<<<64, 512, 0, stream>>>(
        x, d_in[1], d_in[2], d_in[3], d_in[4], d_in[5], d_in[6], d_in[7],
        d_out, force);
}

// Round 7
// 2529.683 us; speedup vs baseline: 34.5180x; 1.7928x over previous
//
#include <hip/hip_runtime.h>
#include <hip/hip_bf16.h>
#include <math.h>

// Elman RNN. VOCAB=50257, EMB=256, HID=512, OUT=2, B=128, T=512.
// R7: register-resident weights (r6, proven VGPR=212) + MALL-coherent h
// exchange. r6's __threadfence() emitted agent-scope L2 writeback+invalidate
// every step (FETCH 437 KB/step, 8.8 us/step). Now all cross-block traffic
// uses agent-scope RELAXED atomics (sc0 sc1 -> execute at MALL, coherent
// across XCDs, zero cache maintenance); ordering via s_waitcnt vmcnt(0) +
// block barriers + control dependency on the spin loop.

#define VOCAB   50257
#define T_STEPS 512
#define HID     512
#define EMB     256
#define XPAD    264
#define HPAD    528
#define BPG     4
#define WS_H    4096                       // counters in [0,4096)
#define WS_NEED (4096 + 2 * 8 * 16 * 256 * 4)   // + packed h: 256 KB

typedef __bf16 bf16x8 __attribute__((ext_vector_type(8)));
typedef float  f32x4  __attribute__((ext_vector_type(4)));

__device__ inline float ldf(const void* p, long i, bool f32) {
    if (f32) return ((const float*)p)[i];
    unsigned bits = ((unsigned)((const unsigned short*)p)[i]) << 16;
    return __uint_as_float(bits);
}
__device__ inline void stf(void* p, long i, float v, bool f32) {
    if (f32) { ((float*)p)[i] = v; return; }
    unsigned b = __float_as_uint(v);
    unsigned r = (b + 0x7fffu + ((b >> 16) & 1u)) >> 16;   // RNE bf16
    ((unsigned short*)p)[i] = (unsigned short)r;
}
__device__ inline unsigned short f2bf(float v) {
    unsigned b = __float_as_uint(v);
    return (unsigned short)((b + 0x7fffu + ((b >> 16) & 1u)) >> 16);
}
__device__ inline int get_tok(const int* x, int idx, bool x64) {
    unsigned u = (unsigned)(x64 ? x[2 * idx] : x[idx]);
    return (u < (unsigned)VOCAB) ? (int)u : 0;
}
__device__ inline int detect_flags(const int* x, const void* emb) {
    int allz = 1;   // floats f32? (bf16-view of f32 emb row0 stays zero)
    const unsigned short* e16 = (const unsigned short*)emb;
    for (int i = 256; i < 320; ++i) allz &= (e16[i] == 0);
    int x64 = 1;    // x int64?
    for (int j = 1; j < 16; j += 2) x64 &= (x[j] == 0);
    return allz | (x64 << 1);
}
__device__ inline float tanh_f(float x) {
    float ax = fabsf(x);
    float e  = __expf(-2.0f * ax);
    float t  = (1.0f - e) * __builtin_amdgcn_rcpf(1.0f + e);
    return copysignf(t, x);
}
__device__ inline void load_xe(const void* emb, long base, bool f32,
                               bf16x8* a, bf16x8* b) {
    if (f32) {
        const float* p = (const float*)emb + base;
        bf16x8 va, vb;
#pragma unroll
        for (int j = 0; j < 8; ++j) va[j] = (__bf16)p[j];
#pragma unroll
        for (int j = 0; j < 8; ++j) vb[j] = (__bf16)p[8 + j];
        *a = va; *b = vb;
    } else {
        const bf16x8* p = (const bf16x8*)((const unsigned short*)emb + base);
        *a = p[0]; *b = p[1];
    }
}

// ---------------- register-resident MFMA scan, MALL exchange ----------------
__global__ __launch_bounds__(256, 1) void scan_mfma(
    const int* __restrict__ x, const void* __restrict__ embv,
    const void* __restrict__ Wwv, const void* __restrict__ Wbv,
    const void* __restrict__ Uwv, const void* __restrict__ Ubv,
    const void* __restrict__ Vwv, const void* __restrict__ Vbv,
    unsigned char* __restrict__ ws, void* __restrict__ outv)
{
    __shared__ __align__(16) __hip_bfloat16 xe_s[16][XPAD];
    __shared__ __align__(16) __hip_bfloat16 hbuf[2][16][HPAD];
    __shared__ int flags_s;

    const int tid = threadIdx.x;
    const int g   = blockIdx.x >> 2;       // batch group (8)
    const int cg  = blockIdx.x & 3;        // column group (4)
    const int b0  = g * 16;

    if (tid == 0) flags_s = detect_flags(x, embv);
    __syncthreads();
    const bool f32w = (flags_s & 1) != 0;
    const bool x64  = (flags_s & 2) != 0;

    const int w = tid >> 6, lane = tid & 63, ln = lane & 15, q = lane >> 4;
    const int n0 = cg * 128 + w * 32 + ln;          // wave's cols: n0, n0+16

    for (int i = tid; i < 2 * 16 * HPAD; i += 256)
        ((__hip_bfloat16*)hbuf)[i] = __float2bfloat16(0.0f);

    // ---- one-time weight fragment loads (registers for all 512 steps) ------
    bf16x8 ufr[2][16], wfr[2][8];
#pragma unroll
    for (int half = 0; half < 2; ++half) {
        const long n = n0 + half * 16;
#pragma unroll
        for (int kt = 0; kt < 16; ++kt) {
            bf16x8 v;
#pragma unroll
            for (int j = 0; j < 8; ++j)
                v[j] = (__bf16)ldf(Uwv, n * HID + kt * 32 + q * 8 + j, f32w);
            ufr[half][kt] = v;
        }
#pragma unroll
        for (int kt = 0; kt < 8; ++kt) {
            bf16x8 v;
#pragma unroll
            for (int j = 0; j < 8; ++j)
                v[j] = (__bf16)ldf(Wwv, n * EMB + kt * 32 + q * 8 + j, f32w);
            wfr[half][kt] = v;
        }
    }
    const float bias0 = ldf(Wbv, n0, f32w)      + ldf(Ubv, n0, f32w);
    const float bias1 = ldf(Wbv, n0 + 16, f32w) + ldf(Ubv, n0 + 16, f32w);

    // xe staging map: thread -> row xr, 16 cols at xc
    const int xr = tid >> 4, xc = (tid & 15) * 16;
    {
        int tok = get_tok(x, (b0 + xr) * T_STEPS + 0, x64);
        bf16x8 xa, xb;
        load_xe(embv, (long)tok * EMB + xc, f32w, &xa, &xb);
        *(bf16x8*)&xe_s[xr][xc]     = xa;
        *(bf16x8*)&xe_s[xr][xc + 8] = xb;
    }
    __syncthreads();

    // packed h in ws: uint word j of (parity,group): [16 rows][256 words];
    // word (row, cg,w,ln) = (bf16(h[row][n0]), bf16(h[row][n0+16]))
    unsigned*           hg32 = (unsigned*)(ws + WS_H);
    unsigned long long* hg64 = (unsigned long long*)(ws + WS_H);
    int*                cnt  = (int*)(void*)ws + g * 32;   // 128 B apart

    for (int t = 0; t < T_STEPS; ++t) {
        bf16x8 nxa, nxb;
        const bool have_next = (t + 1 < T_STEPS);
        if (have_next) {
            int tok = get_tok(x, (b0 + xr) * T_STEPS + (t + 1), x64);
            load_xe(embv, (long)tok * EMB + xc, f32w, &nxa, &nxb);
        }

        f32x4 acc0, acc1;
#pragma unroll
        for (int r = 0; r < 4; ++r) { acc0[r] = bias0; acc1[r] = bias1; }

        // wx phase: [16 x 256] @ Ww^T
#pragma unroll
        for (int kt = 0; kt < 8; ++kt) {
            bf16x8 a = *(const bf16x8*)&xe_s[ln][kt * 32 + q * 8];
            acc0 = __builtin_amdgcn_mfma_f32_16x16x32_bf16(a, wfr[0][kt], acc0, 0, 0, 0);
            acc1 = __builtin_amdgcn_mfma_f32_16x16x32_bf16(a, wfr[1][kt], acc1, 0, 0, 0);
        }
        // recurrent phase: [16 x 512] @ Uw^T
        const __hip_bfloat16 (*hr)[HPAD] = hbuf[t & 1];
#pragma unroll
        for (int kt = 0; kt < 16; ++kt) {
            bf16x8 a = *(const bf16x8*)&hr[ln][kt * 32 + q * 8];
            acc0 = __builtin_amdgcn_mfma_f32_16x16x32_bf16(a, ufr[0][kt], acc0, 0, 0, 0);
            acc1 = __builtin_amdgcn_mfma_f32_16x16x32_bf16(a, ufr[1][kt], acc1, 0, 0, 0);
        }

        // publish own 32-col slice: agent-relaxed atomic stores -> MALL
        const int nb = (t + 1) & 1;
        {
            unsigned* dst = hg32 + (size_t)(nb * 8 + g) * 4096 + cg * 64 + w * 16 + ln;
#pragma unroll
            for (int r = 0; r < 4; ++r) {
                unsigned word = (unsigned)f2bf(tanh_f(acc0[r]))
                              | ((unsigned)f2bf(tanh_f(acc1[r])) << 16);
                __hip_atomic_store(dst + (size_t)(q * 4 + r) * 256, word,
                                   __ATOMIC_RELAXED, __HIP_MEMORY_SCOPE_AGENT);
            }
        }
        asm volatile("s_waitcnt vmcnt(0)" ::: "memory");   // stores at MALL
        __syncthreads();                                    // all waves drained

        if (have_next) {                    // stage xe(t+1) (xe_s reads done)
            *(bf16x8*)&xe_s[xr][xc]     = nxa;
            *(bf16x8*)&xe_s[xr][xc + 8] = nxb;
        }

        if (tid == 0) {
            __hip_atomic_fetch_add(cnt, 1, __ATOMIC_RELAXED,
                                   __HIP_MEMORY_SCOPE_AGENT);
            const int target = BPG * (t + 1);
            while (__hip_atomic_load(cnt, __ATOMIC_RELAXED,
                                     __HIP_MEMORY_SCOPE_AGENT) < target)
                __builtin_amdgcn_s_sleep(1);
        }
        __syncthreads();   // spin exit -> control-dep; loads below are ordered

        // read back full h_{t+1} (16 KB) from MALL -> LDS hbuf[nb]
        {
            const unsigned long long* src = hg64 + (size_t)(nb * 8 + g) * 2048;
#pragma unroll
            for (int m = tid; m < 2048; m += 256) {
                unsigned long long v = __hip_atomic_load(
                    src + m, __ATOMIC_RELAXED, __HIP_MEMORY_SCOPE_AGENT);
                int row = m >> 7, p = m & 127;
                int j0  = 2 * p;
                int cgp = j0 >> 6, wv = (j0 >> 4) & 3, l0 = j0 & 15;
                int colA = cgp * 128 + wv * 32 + l0;       // even
                unsigned w0 = (unsigned)v, w1 = (unsigned)(v >> 32);
                unsigned lo = (w0 & 0xffffu) | (w1 << 16);            // cols A,A+1
                unsigned hi = (w0 >> 16) | (w1 & 0xffff0000u);        // cols A+16,A+17
                *(unsigned*)&hbuf[nb][row][colA]      = lo;
                *(unsigned*)&hbuf[nb][row][colA + 16] = hi;
            }
        }
        __syncthreads();
    }

    // logits = hT @ Vw^T + Vb ; full h_T in hbuf[0] (T even); cg0 writes
    if (cg == 0) {
        int b = tid >> 4, rem = tid & 15, o = rem >> 3, kp = rem & 7;
        float s = 0.0f;
#pragma unroll 4
        for (int j = 0; j < 64; ++j) {
            int k = kp * 64 + j;
            s += __bfloat162float(hbuf[0][b][k]) * ldf(Vwv, (long)o * HID + k, f32w);
        }
        s += __shfl_xor(s, 1);
        s += __shfl_xor(s, 2);
        s += __shfl_xor(s, 4);
        if (kp == 0)
            stf(outv, (long)(b0 + b) * 2 + o, s + ldf(Vbv, o, f32w), f32w);
    }
}

// ---------------- fixup: NaN net + forced-anchor fallback -------------------
#define B_PER 2
__global__ __launch_bounds__(512) void fixup(
    const int* __restrict__ x, const void* __restrict__ emb,
    const void* __restrict__ Ww, const void* __restrict__ Wb,
    const void* __restrict__ Uw, const void* __restrict__ Ub,
    const void* __restrict__ Vw, const void* __restrict__ Vb,
    void* __restrict__ out, int force)
{
    __shared__ float h_s[2][B_PER][HID];
    __shared__ float xe_s[B_PER][EMB];
    __shared__ int   flags_s, bad_s;

    const int tid = threadIdx.x;
    const int b0  = blockIdx.x * B_PER;

    if (tid == 0) {
        int fl = detect_flags(x, emb);
        flags_s = fl;
        int bad = force;
        if (!force) {
            bool f32o = (fl & 1) != 0;
            for (int i = 0; i < 2 * B_PER; ++i) {
                int oi = b0 * 2 + i;
                if (f32o) {
                    float v = ((const float*)out)[oi];
                    bad |= (v != v);
                } else {
                    unsigned short u = ((const unsigned short*)out)[oi];
                    bad |= (((u & 0x7F80u) == 0x7F80u) && ((u & 0x7Fu) != 0));
                }
            }
        }
        bad_s = bad;
    }
    __syncthreads();
    if (!bad_s) return;

    const bool f32w = (flags_s & 1) != 0;
    const bool x64  = (flags_s & 2) != 0;
    const int n = tid;
    const float bias = ldf(Wb, n, f32w) + ldf(Ub, n, f32w);

    for (int b = 0; b < B_PER; ++b) h_s[0][b][n] = 0.0f;

    for (int t = 0; t < T_STEPS; ++t) {
        {
            int b = tid >> 8, c = tid & 255;
            int tok = get_tok(x, (b0 + b) * T_STEPS + t, x64);
            xe_s[b][c] = ldf(emb, (long)tok * EMB + c, f32w);
        }
        __syncthreads();

        float acc0 = bias, acc1 = bias;
        const long wrow = (long)n * EMB;
#pragma unroll 8
        for (int k = 0; k < EMB; ++k) {
            float wv = ldf(Ww, wrow + k, f32w);
            acc0 += xe_s[0][k] * wv;
            acc1 += xe_s[1][k] * wv;
        }
        const long urow = (long)n * HID;
        const float* hc0 = h_s[t & 1][0];
        const float* hc1 = h_s[t & 1][1];
#pragma unroll 8
        for (int k = 0; k < HID; ++k) {
            float uv = ldf(Uw, urow + k, f32w);
            acc0 += hc0[k] * uv;
            acc1 += hc1[k] * uv;
        }
        h_s[(t + 1) & 1][0][n] = tanhf(acc0);
        h_s[(t + 1) & 1][1][n] = tanhf(acc1);
        __syncthreads();
    }

    if (tid < 2 * B_PER) {
        int b = tid >> 1, o = tid & 1;
        float s = ldf(Vb, o, f32w);
        for (int k = 0; k < HID; ++k)
            s += h_s[0][b][k] * ldf(Vw, (long)o * HID + k, f32w);
        stf(out, (b0 + b) * 2 + o, s, f32w);
    }
}

extern "C" void kernel_launch(void* const* d_in, const int* in_sizes, int n_in,
                              void* d_out, int out_size, void* d_ws, size_t ws_size,
                              hipStream_t stream) {
    const int* x = (const int*)d_in[0];
    const int force = (ws_size < (size_t)WS_NEED) ? 1 : 0;
    if (!force) {
        hipMemsetAsync(d_ws, 0, 4096, stream);       // zero barrier counters
        scan_mfma<<<32, 256, 0, stream>>>(
            x, d_in[1], d_in[2], d_in[3], d_in[4], d_in[5], d_in[6], d_in[7],
            (unsigned char*)d_ws, d_out);
    }
    fixup<<<64, 512, 0, stream>>>(
        x, d_in[1], d_in[2], d_in[3], d_in[4], d_in[5], d_in[6], d_in[7],
        d_out, force);
}

// Round 8
// 1697.351 us; speedup vs baseline: 51.4446x; 1.4904x over previous
//
#include <hip/hip_runtime.h>
#include <hip/hip_bf16.h>
#include <math.h>

// Elman RNN. VOCAB=50257, EMB=256, HID=512, OUT=2, B=128, T=512.
// R8: kill the cross-CU exchange (93% of r7's step time).
//  1) wx_gemm: bf16 MFMA GEMM computes wx[t][b][n] = xe@Ww^T + Wb + Ub for all
//     (t,b) into d_ws (bf16; f32 if ws >= 128 MB). Massively parallel, ~20 us.
//  2) scan_i8: 8 blocks x 512 thr, ONE CU per batch-group. Uw quantized to
//     int8 (scale = max|Uw|/127) -> 256 KB -> fully register-resident across
//     the CU's 8 waves (128 VGPR/thread). Per step: LDS-only h exchange,
//     one barrier, zero global traffic on the critical path (wx prefetched).
//  Fallbacks: ws < 64 MB -> r7 MALL-exchange scan; ws < 260 KB -> anchor.

#define VOCAB   50257
#define T_STEPS 512
#define HID     512
#define EMB     256

typedef __bf16 bf16x8 __attribute__((ext_vector_type(8)));
typedef float  f32x4  __attribute__((ext_vector_type(4)));
typedef int    i32x4  __attribute__((ext_vector_type(4)));

__device__ inline float ldf(const void* p, long i, bool f32) {
    if (f32) return ((const float*)p)[i];
    unsigned bits = ((unsigned)((const unsigned short*)p)[i]) << 16;
    return __uint_as_float(bits);
}
__device__ inline void stf(void* p, long i, float v, bool f32) {
    if (f32) { ((float*)p)[i] = v; return; }
    unsigned b = __float_as_uint(v);
    unsigned r = (b + 0x7fffu + ((b >> 16) & 1u)) >> 16;   // RNE bf16
    ((unsigned short*)p)[i] = (unsigned short)r;
}
__device__ inline unsigned short f2bf(float v) {
    unsigned b = __float_as_uint(v);
    return (unsigned short)((b + 0x7fffu + ((b >> 16) & 1u)) >> 16);
}
__device__ inline float bf2f(unsigned short u) {
    return __uint_as_float(((unsigned)u) << 16);
}
__device__ inline int get_tok(const int* x, int idx, bool x64) {
    unsigned u = (unsigned)(x64 ? x[2 * idx] : x[idx]);
    return (u < (unsigned)VOCAB) ? (int)u : 0;
}
__device__ inline int detect_flags(const int* x, const void* emb) {
    int allz = 1;   // floats f32? (bf16-view of f32 emb row0 stays zero)
    const unsigned short* e16 = (const unsigned short*)emb;
    for (int i = 256; i < 320; ++i) allz &= (e16[i] == 0);
    int x64 = 1;    // x int64?
    for (int j = 1; j < 16; j += 2) x64 &= (x[j] == 0);
    return allz | (x64 << 1);
}
__device__ inline float tanh_f(float x) {
    float ax = fabsf(x);
    float e  = __expf(-2.0f * ax);
    float t  = (1.0f - e) * __builtin_amdgcn_rcpf(1.0f + e);
    return copysignf(t, x);
}

// =================== kernel 1: wx = xe@Ww^T + Wb + Ub =======================
// grid 512 (one block per t) x 512 thr (8 waves). Wave w owns cols [64w,64w+64)
// as 4 n-tiles; Ww frags register-resident; xe staged in 64-row LDS halves.
#define XEPAD 264
__global__ __launch_bounds__(512, 2) void wx_gemm(
    const int* __restrict__ x, const void* __restrict__ embv,
    const void* __restrict__ Wwv, const void* __restrict__ Wbv,
    const void* __restrict__ Ubv, unsigned char* __restrict__ ws, int wxf32)
{
    __shared__ __align__(16) __hip_bfloat16 xe_s[64][XEPAD];   // 33.8 KB
    __shared__ int flags_s;
    const int t = blockIdx.x, tid = threadIdx.x;
    if (tid == 0) flags_s = detect_flags(x, embv);
    __syncthreads();
    const bool f32w = (flags_s & 1) != 0;
    const bool x64  = (flags_s & 2) != 0;

    const int w = tid >> 6, lane = tid & 63, ln = lane & 15, q = lane >> 4;

    // loop-invariant: B-frags of Ww + bias, register-resident
    bf16x8 bf[4][8];
    float  bias[4];
#pragma unroll
    for (int tn = 0; tn < 4; ++tn) {
        long n = w * 64 + tn * 16 + ln;
        bias[tn] = ldf(Wbv, n, f32w) + ldf(Ubv, n, f32w);
#pragma unroll
        for (int kt = 0; kt < 8; ++kt) {
            bf16x8 v;
#pragma unroll
            for (int j = 0; j < 8; ++j)
                v[j] = (__bf16)ldf(Wwv, n * EMB + kt * 32 + q * 8 + j, f32w);
            bf[tn][kt] = v;
        }
    }

    for (int half = 0; half < 2; ++half) {
        // stage xe rows [64*half, 64*half+64): 8 threads/row, 32 cols each
        {
            int row = tid >> 3, sub = tid & 7;
            int tok = get_tok(x, (half * 64 + row) * T_STEPS + t, x64);
            long base = (long)tok * EMB + sub * 32;
#pragma unroll 8
            for (int i = 0; i < 32; ++i)
                xe_s[row][sub * 32 + i] = __float2bfloat16(ldf(embv, base + i, f32w));
        }
        __syncthreads();

        for (int bt = 0; bt < 4; ++bt) {
            f32x4 acc[4];
#pragma unroll
            for (int tn = 0; tn < 4; ++tn)
#pragma unroll
                for (int r = 0; r < 4; ++r) acc[tn][r] = bias[tn];
#pragma unroll
            for (int kt = 0; kt < 8; ++kt) {
                bf16x8 a = *(const bf16x8*)&xe_s[bt * 16 + ln][kt * 32 + q * 8];
#pragma unroll
                for (int tn = 0; tn < 4; ++tn)
                    acc[tn] = __builtin_amdgcn_mfma_f32_16x16x32_bf16(
                        a, bf[tn][kt], acc[tn], 0, 0, 0);
            }
            // C/D: batch row = half*64 + bt*16 + q*4 + r, col = w*64+tn*16+ln
#pragma unroll
            for (int tn = 0; tn < 4; ++tn)
#pragma unroll
                for (int r = 0; r < 4; ++r) {
                    long idx = ((long)t * 128 + half * 64 + bt * 16 + q * 4 + r) * 512
                             + w * 64 + tn * 16 + ln;
                    if (wxf32) ((float*)ws)[idx] = acc[tn][r];
                    else ((unsigned short*)ws)[idx] = f2bf(acc[tn][r]);
                }
        }
        __syncthreads();   // xe_s reads done before re-stage
    }
}

// =================== kernel 2: single-CU i8 scan ============================
// 8 blocks x 512 thr. Block g owns batches [16g,16g+16). Wave w owns cols
// [64w, 64w+64) as 4 n-tiles. Uw int8 fragments in VGPRs (128/thread).
#define HQP 528
__global__ __launch_bounds__(512, 2) void scan_i8(
    const void* __restrict__ Uwv, const void* __restrict__ Vwv,
    const void* __restrict__ Vbv, const int* __restrict__ x,
    const void* __restrict__ embv, const unsigned char* __restrict__ wsc,
    int wxf32, void* __restrict__ outv)
{
    __shared__ __align__(16) signed char hq[2][16][HQP];   // 16.9 KB ping-pong
    __shared__ float red[512];
    __shared__ int flags_s;

    const int tid = threadIdx.x, g = blockIdx.x, b0 = g * 16;
    if (tid == 0) flags_s = detect_flags(x, embv);
    __syncthreads();
    const bool f32w = (flags_s & 1) != 0;

    const int w = tid >> 6, lane = tid & 63, ln = lane & 15, q = lane >> 4;

    // ---- su = max|Uw| (block-local, deterministic across blocks) -----------
    {
        float mx = 0.0f;
        long base = (long)tid * 512;
        for (int i = 0; i < 512; ++i)
            mx = fmaxf(mx, fabsf(ldf(Uwv, base + i, f32w)));
        red[tid] = mx;
        __syncthreads();
        for (int s = 256; s > 0; s >>= 1) {
            if (tid < s) red[tid] = fmaxf(red[tid], red[tid + s]);
            __syncthreads();
        }
    }
    const float su = red[0];
    const float qs = 127.0f / su;
    const float sc = su / 16129.0f;          // su/(127*127)

    // ---- quantize Uw -> register-resident i8 B-frags -----------------------
    // B[k=kt*32+q*8+j][n=w*64+tn*16+ln] = Uw[n][k]; 8 bytes packed per frag.
    unsigned long long uq[4][16];
#pragma unroll
    for (int tn = 0; tn < 4; ++tn) {
        long n = w * 64 + tn * 16 + ln;
#pragma unroll
        for (int kt = 0; kt < 16; ++kt) {
            unsigned long long pk = 0;
#pragma unroll
            for (int j = 0; j < 8; ++j) {
                float v = ldf(Uwv, n * HID + kt * 32 + q * 8 + j, f32w) * qs;
                int   qv = (int)__builtin_rintf(v);
                qv = qv > 127 ? 127 : (qv < -127 ? -127 : qv);
                pk |= ((unsigned long long)(unsigned char)(signed char)qv) << (8 * j);
            }
            uq[tn][kt] = pk;
        }
    }

    // h0 = 0
    for (int i = tid; i < 16 * HQP; i += 512) ((signed char*)hq[0])[i] = 0;

    // wx(t=0) into wxc
    float wxc[16], wxn[16];
#pragma unroll
    for (int tn = 0; tn < 4; ++tn)
#pragma unroll
        for (int r = 0; r < 4; ++r) {
            long idx = ((long)0 * 128 + b0 + q * 4 + r) * 512 + w * 64 + tn * 16 + ln;
            wxc[tn * 4 + r] = wxf32 ? ((const float*)wsc)[idx]
                                    : bf2f(((const unsigned short*)wsc)[idx]);
        }
    __syncthreads();

    for (int t = 0; t < T_STEPS; ++t) {
        // prefetch wx(t+1) (independent of h; consumed next step)
        {
            int tn1 = (t + 1 < T_STEPS) ? (t + 1) : t;
#pragma unroll
            for (int tn = 0; tn < 4; ++tn)
#pragma unroll
                for (int r = 0; r < 4; ++r) {
                    long idx = ((long)tn1 * 128 + b0 + q * 4 + r) * 512
                             + w * 64 + tn * 16 + ln;
                    wxn[tn * 4 + r] = wxf32 ? ((const float*)wsc)[idx]
                                            : bf2f(((const unsigned short*)wsc)[idx]);
                }
        }

        i32x4 acc[4];
#pragma unroll
        for (int tn = 0; tn < 4; ++tn)
#pragma unroll
            for (int r = 0; r < 4; ++r) acc[tn][r] = 0;

        const signed char (*hr)[HQP] = hq[t & 1];
#pragma unroll
        for (int kt = 0; kt < 16; ++kt) {
            long long a = *(const long long*)&hr[ln][kt * 32 + q * 8];
#pragma unroll
            for (int tn = 0; tn < 4; ++tn)
                acc[tn] = __builtin_amdgcn_mfma_i32_16x16x32_i8(
                    a, (long long)uq[tn][kt], acc[tn], 0, 0, 0);
        }

        // epilogue: v = wx + acc*sc ; h' = tanh(v) -> i8 into other buffer
        signed char (*hw)[HQP] = hq[(t + 1) & 1];
#pragma unroll
        for (int tn = 0; tn < 4; ++tn)
#pragma unroll
            for (int r = 0; r < 4; ++r) {
                float v  = wxc[tn * 4 + r] + (float)acc[tn][r] * sc;
                float th = tanh_f(v);
                int   qv = (int)__builtin_rintf(th * 127.0f);
                qv = qv > 127 ? 127 : (qv < -127 ? -127 : qv);
                hw[q * 4 + r][w * 64 + tn * 16 + ln] = (signed char)qv;
            }
#pragma unroll
        for (int i = 0; i < 16; ++i) wxc[i] = wxn[i];
        __syncthreads();   // h' sealed; next step reads it
    }

    // logits = hT @ Vw^T + Vb ; final h in hq[0] (T even)
    {
        int b = tid >> 5, o = (tid >> 4) & 1, kp = tid & 15;
        float s = 0.0f;
#pragma unroll 4
        for (int j = 0; j < 32; ++j) {
            int k = kp * 32 + j;
            s += (float)hq[0][b][k] * (1.0f / 127.0f) * ldf(Vwv, (long)o * HID + k, f32w);
        }
        s += __shfl_xor(s, 1);
        s += __shfl_xor(s, 2);
        s += __shfl_xor(s, 4);
        s += __shfl_xor(s, 8);
        if (kp == 0)
            stf(outv, (long)(b0 + b) * 2 + o, s + ldf(Vbv, o, f32w), f32w);
    }
}

// =================== fallback: r7 MALL-exchange scan (proven) ===============
#define XPAD 264
#define HPAD 528
#define BPG  4
#define R7_WS_H   4096
#define R7_WS_NEED (4096 + 2 * 8 * 16 * 256 * 4)

__device__ inline void load_xe(const void* emb, long base, bool f32,
                               bf16x8* a, bf16x8* b) {
    if (f32) {
        const float* p = (const float*)emb + base;
        bf16x8 va, vb;
#pragma unroll
        for (int j = 0; j < 8; ++j) va[j] = (__bf16)p[j];
#pragma unroll
        for (int j = 0; j < 8; ++j) vb[j] = (__bf16)p[8 + j];
        *a = va; *b = vb;
    } else {
        const bf16x8* p = (const bf16x8*)((const unsigned short*)emb + base);
        *a = p[0]; *b = p[1];
    }
}

__global__ __launch_bounds__(256, 1) void scan_mfma_fb(
    const int* __restrict__ x, const void* __restrict__ embv,
    const void* __restrict__ Wwv, const void* __restrict__ Wbv,
    const void* __restrict__ Uwv, const void* __restrict__ Ubv,
    const void* __restrict__ Vwv, const void* __restrict__ Vbv,
    unsigned char* __restrict__ ws, void* __restrict__ outv)
{
    __shared__ __align__(16) __hip_bfloat16 xe_s[16][XPAD];
    __shared__ __align__(16) __hip_bfloat16 hbuf[2][16][HPAD];
    __shared__ int flags_s;

    const int tid = threadIdx.x;
    const int g   = blockIdx.x >> 2;
    const int cg  = blockIdx.x & 3;
    const int b0  = g * 16;

    if (tid == 0) flags_s = detect_flags(x, embv);
    __syncthreads();
    const bool f32w = (flags_s & 1) != 0;
    const bool x64  = (flags_s & 2) != 0;

    const int w = tid >> 6, lane = tid & 63, ln = lane & 15, q = lane >> 4;
    const int n0 = cg * 128 + w * 32 + ln;

    for (int i = tid; i < 2 * 16 * HPAD; i += 256)
        ((__hip_bfloat16*)hbuf)[i] = __float2bfloat16(0.0f);

    bf16x8 ufr[2][16], wfr[2][8];
#pragma unroll
    for (int half = 0; half < 2; ++half) {
        const long n = n0 + half * 16;
#pragma unroll
        for (int kt = 0; kt < 16; ++kt) {
            bf16x8 v;
#pragma unroll
            for (int j = 0; j < 8; ++j)
                v[j] = (__bf16)ldf(Uwv, n * HID + kt * 32 + q * 8 + j, f32w);
            ufr[half][kt] = v;
        }
#pragma unroll
        for (int kt = 0; kt < 8; ++kt) {
            bf16x8 v;
#pragma unroll
            for (int j = 0; j < 8; ++j)
                v[j] = (__bf16)ldf(Wwv, n * EMB + kt * 32 + q * 8 + j, f32w);
            wfr[half][kt] = v;
        }
    }
    const float bias0 = ldf(Wbv, n0, f32w)      + ldf(Ubv, n0, f32w);
    const float bias1 = ldf(Wbv, n0 + 16, f32w) + ldf(Ubv, n0 + 16, f32w);

    const int xr = tid >> 4, xc = (tid & 15) * 16;
    {
        int tok = get_tok(x, (b0 + xr) * T_STEPS + 0, x64);
        bf16x8 xa, xb;
        load_xe(embv, (long)tok * EMB + xc, f32w, &xa, &xb);
        *(bf16x8*)&xe_s[xr][xc]     = xa;
        *(bf16x8*)&xe_s[xr][xc + 8] = xb;
    }
    __syncthreads();

    unsigned*           hg32 = (unsigned*)(ws + R7_WS_H);
    unsigned long long* hg64 = (unsigned long long*)(ws + R7_WS_H);
    int*                cnt  = (int*)(void*)ws + g * 32;

    for (int t = 0; t < T_STEPS; ++t) {
        bf16x8 nxa, nxb;
        const bool have_next = (t + 1 < T_STEPS);
        if (have_next) {
            int tok = get_tok(x, (b0 + xr) * T_STEPS + (t + 1), x64);
            load_xe(embv, (long)tok * EMB + xc, f32w, &nxa, &nxb);
        }

        f32x4 acc0, acc1;
#pragma unroll
        for (int r = 0; r < 4; ++r) { acc0[r] = bias0; acc1[r] = bias1; }
#pragma unroll
        for (int kt = 0; kt < 8; ++kt) {
            bf16x8 a = *(const bf16x8*)&xe_s[ln][kt * 32 + q * 8];
            acc0 = __builtin_amdgcn_mfma_f32_16x16x32_bf16(a, wfr[0][kt], acc0, 0, 0, 0);
            acc1 = __builtin_amdgcn_mfma_f32_16x16x32_bf16(a, wfr[1][kt], acc1, 0, 0, 0);
        }
        const __hip_bfloat16 (*hr)[HPAD] = hbuf[t & 1];
#pragma unroll
        for (int kt = 0; kt < 16; ++kt) {
            bf16x8 a = *(const bf16x8*)&hr[ln][kt * 32 + q * 8];
            acc0 = __builtin_amdgcn_mfma_f32_16x16x32_bf16(a, ufr[0][kt], acc0, 0, 0, 0);
            acc1 = __builtin_amdgcn_mfma_f32_16x16x32_bf16(a, ufr[1][kt], acc1, 0, 0, 0);
        }

        const int nb = (t + 1) & 1;
        {
            unsigned* dst = hg32 + (size_t)(nb * 8 + g) * 4096 + cg * 64 + w * 16 + ln;
#pragma unroll
            for (int r = 0; r < 4; ++r) {
                unsigned word = (unsigned)f2bf(tanh_f(acc0[r]))
                              | ((unsigned)f2bf(tanh_f(acc1[r])) << 16);
                __hip_atomic_store(dst + (size_t)(q * 4 + r) * 256, word,
                                   __ATOMIC_RELAXED, __HIP_MEMORY_SCOPE_AGENT);
            }
        }
        asm volatile("s_waitcnt vmcnt(0)" ::: "memory");
        __syncthreads();

        if (have_next) {
            *(bf16x8*)&xe_s[xr][xc]     = nxa;
            *(bf16x8*)&xe_s[xr][xc + 8] = nxb;
        }

        if (tid == 0) {
            __hip_atomic_fetch_add(cnt, 1, __ATOMIC_RELAXED,
                                   __HIP_MEMORY_SCOPE_AGENT);
            const int target = BPG * (t + 1);
            while (__hip_atomic_load(cnt, __ATOMIC_RELAXED,
                                     __HIP_MEMORY_SCOPE_AGENT) < target)
                __builtin_amdgcn_s_sleep(1);
        }
        __syncthreads();

        {
            const unsigned long long* src = hg64 + (size_t)(nb * 8 + g) * 2048;
#pragma unroll
            for (int m = tid; m < 2048; m += 256) {
                unsigned long long v = __hip_atomic_load(
                    src + m, __ATOMIC_RELAXED, __HIP_MEMORY_SCOPE_AGENT);
                int row = m >> 7, p = m & 127;
                int j0  = 2 * p;
                int cgp = j0 >> 6, wv = (j0 >> 4) & 3, l0 = j0 & 15;
                int colA = cgp * 128 + wv * 32 + l0;
                unsigned w0 = (unsigned)v, w1 = (unsigned)(v >> 32);
                unsigned lo = (w0 & 0xffffu) | (w1 << 16);
                unsigned hi = (w0 >> 16) | (w1 & 0xffff0000u);
                *(unsigned*)&hbuf[nb][row][colA]      = lo;
                *(unsigned*)&hbuf[nb][row][colA + 16] = hi;
            }
        }
        __syncthreads();
    }

    if (cg == 0) {
        int b = tid >> 4, rem = tid & 15, o = rem >> 3, kp = rem & 7;
        float s = 0.0f;
#pragma unroll 4
        for (int j = 0; j < 64; ++j) {
            int k = kp * 64 + j;
            s += __bfloat162float(hbuf[0][b][k]) * ldf(Vwv, (long)o * HID + k, f32w);
        }
        s += __shfl_xor(s, 1);
        s += __shfl_xor(s, 2);
        s += __shfl_xor(s, 4);
        if (kp == 0)
            stf(outv, (long)(b0 + b) * 2 + o, s + ldf(Vbv, o, f32w), f32w);
    }
}

// =================== fixup: NaN net + forced-anchor fallback ================
#define B_PER 2
__global__ __launch_bounds__(512) void fixup(
    const int* __restrict__ x, const void* __restrict__ emb,
    const void* __restrict__ Ww, const void* __restrict__ Wb,
    const void* __restrict__ Uw, const void* __restrict__ Ub,
    const void* __restrict__ Vw, const void* __restrict__ Vb,
    void* __restrict__ out, int force)
{
    __shared__ float h_s[2][B_PER][HID];
    __shared__ float xe_sf[B_PER][EMB];
    __shared__ int   flags_s, bad_s;

    const int tid = threadIdx.x;
    const int b0  = blockIdx.x * B_PER;

    if (tid == 0) {
        int fl = detect_flags(x, emb);
        flags_s = fl;
        int bad = force;
        if (!force) {
            bool f32o = (fl & 1) != 0;
            for (int i = 0; i < 2 * B_PER; ++i) {
                int oi = b0 * 2 + i;
                if (f32o) {
                    float v = ((const float*)out)[oi];
                    bad |= (v != v);
                } else {
                    unsigned short u = ((const unsigned short*)out)[oi];
                    bad |= (((u & 0x7F80u) == 0x7F80u) && ((u & 0x7Fu) != 0));
                }
            }
        }
        bad_s = bad;
    }
    __syncthreads();
    if (!bad_s) return;

    const bool f32w = (flags_s & 1) != 0;
    const bool x64  = (flags_s & 2) != 0;
    const int n = tid;
    const float bias = ldf(Wb, n, f32w) + ldf(Ub, n, f32w);

    for (int b = 0; b < B_PER; ++b) h_s[0][b][n] = 0.0f;

    for (int t = 0; t < T_STEPS; ++t) {
        {
            int b = tid >> 8, c = tid & 255;
            int tok = get_tok(x, (b0 + b) * T_STEPS + t, x64);
            xe_sf[b][c] = ldf(emb, (long)tok * EMB + c, f32w);
        }
        __syncthreads();

        float acc0 = bias, acc1 = bias;
        const long wrow = (long)n * EMB;
#pragma unroll 8
        for (int k = 0; k < EMB; ++k) {
            float wv = ldf(Ww, wrow + k, f32w);
            acc0 += xe_sf[0][k] * wv;
            acc1 += xe_sf[1][k] * wv;
        }
        const long urow = (long)n * HID;
        const float* hc0 = h_s[t & 1][0];
        const float* hc1 = h_s[t & 1][1];
#pragma unroll 8
        for (int k = 0; k < HID; ++k) {
            float uv = ldf(Uw, urow + k, f32w);
            acc0 += hc0[k] * uv;
            acc1 += hc1[k] * uv;
        }
        h_s[(t + 1) & 1][0][n] = tanhf(acc0);
        h_s[(t + 1) & 1][1][n] = tanhf(acc1);
        __syncthreads();
    }

    if (tid < 2 * B_PER) {
        int b = tid >> 1, o = tid & 1;
        float s = ldf(Vb, o, f32w);
        for (int k = 0; k < HID; ++k)
            s += h_s[0][b][k] * ldf(Vw, (long)o * HID + k, f32w);
        stf(out, (b0 + b) * 2 + o, s, f32w);
    }
}

extern "C" void kernel_launch(void* const* d_in, const int* in_sizes, int n_in,
                              void* d_out, int out_size, void* d_ws, size_t ws_size,
                              hipStream_t stream) {
    const int* x = (const int*)d_in[0];
    const size_t WX16 = (size_t)T_STEPS * 128 * 512 * 2;   // 64 MB bf16
    const size_t WX32 = WX16 * 2;                           // 128 MB f32
    if (ws_size >= WX16) {
        const int wxf32 = (ws_size >= WX32) ? 1 : 0;
        wx_gemm<<<512, 512, 0, stream>>>(
            x, d_in[1], d_in[2], d_in[3], d_in[5], (unsigned char*)d_ws, wxf32);
        scan_i8<<<8, 512, 0, stream>>>(
            d_in[4], d_in[6], d_in[7], x, d_in[1],
            (const unsigned char*)d_ws, wxf32, d_out);
        fixup<<<64, 512, 0, stream>>>(
            x, d_in[1], d_in[2], d_in[3], d_in[4], d_in[5], d_in[6], d_in[7],
            d_out, 0);
    } else if (ws_size >= (size_t)R7_WS_NEED) {
        hipMemsetAsync(d_ws, 0, 4096, stream);
        scan_mfma_fb<<<32, 256, 0, stream>>>(
            x, d_in[1], d_in[2], d_in[3], d_in[4], d_in[5], d_in[6], d_in[7],
            (unsigned char*)d_ws, d_out);
        fixup<<<64, 512, 0, stream>>>(
            x, d_in[1], d_in[2], d_in[3], d_in[4], d_in[5], d_in[6], d_in[7],
            d_out, 0);
    } else {
        fixup<<<64, 512, 0, stream>>>(
            x, d_in[1], d_in[2], d_in[3], d_in[4], d_in[5], d_in[6], d_in[7],
            d_out, 1);
    }
}

// Round 9
// 1271.699 us; speedup vs baseline: 68.6637x; 1.3347x over previous
//
#include <hip/hip_runtime.h>
#include <hip/hip_bf16.h>
#include <math.h>

// Elman RNN. VOCAB=50257, EMB=256, HID=512, OUT=2, B=128, T=512.
// R9: r8 structure, occupancy-repaired. r8's __launch_bounds__(512,2) capped
// VGPR at 128 while uq[4][16] alone needs 128 -> spill/AGPR traffic at 2
// waves/SIMD (2.75 us/step). Now: scan = 1024 thr / 16 waves, wave owns 32
// cols, uq[2][16]=64 VGPR (total ~110, fits the 128 cap at 4 waves/SIMD),
// fused branch-free tanh+quantize. wx_gemm same treatment (bf[2][8]=32 regs,
// float4 gather). Fallbacks: r7 MALL scan (ws small), anchor, NaN-net fixup.

#define VOCAB   50257
#define T_STEPS 512
#define HID     512
#define EMB     256

typedef __bf16 bf16x8 __attribute__((ext_vector_type(8)));
typedef float  f32x4  __attribute__((ext_vector_type(4)));
typedef int    i32x4  __attribute__((ext_vector_type(4)));

__device__ inline float ldf(const void* p, long i, bool f32) {
    if (f32) return ((const float*)p)[i];
    unsigned bits = ((unsigned)((const unsigned short*)p)[i]) << 16;
    return __uint_as_float(bits);
}
__device__ inline void stf(void* p, long i, float v, bool f32) {
    if (f32) { ((float*)p)[i] = v; return; }
    unsigned b = __float_as_uint(v);
    unsigned r = (b + 0x7fffu + ((b >> 16) & 1u)) >> 16;   // RNE bf16
    ((unsigned short*)p)[i] = (unsigned short)r;
}
__device__ inline unsigned short f2bf(float v) {
    unsigned b = __float_as_uint(v);
    return (unsigned short)((b + 0x7fffu + ((b >> 16) & 1u)) >> 16);
}
__device__ inline float bf2f(unsigned short u) {
    return __uint_as_float(((unsigned)u) << 16);
}
__device__ inline int get_tok(const int* x, int idx, bool x64) {
    unsigned u = (unsigned)(x64 ? x[2 * idx] : x[idx]);
    return (u < (unsigned)VOCAB) ? (int)u : 0;
}
__device__ inline int detect_flags(const int* x, const void* emb) {
    int allz = 1;   // floats f32? (bf16-view of f32 emb row0 stays zero)
    const unsigned short* e16 = (const unsigned short*)emb;
    for (int i = 256; i < 320; ++i) allz &= (e16[i] == 0);
    int x64 = 1;    // x int64?
    for (int j = 1; j < 16; j += 2) x64 &= (x[j] == 0);
    return allz | (x64 << 1);
}
__device__ inline float tanh_f(float x) {
    float ax = fabsf(x);
    float e  = __expf(-2.0f * ax);
    float t  = (1.0f - e) * __builtin_amdgcn_rcpf(1.0f + e);
    return copysignf(t, x);
}

// =================== kernel 1: wx = xe@Ww^T + Wb + Ub (bf16 out) ============
// grid 512 (one block per t) x 1024 thr (16 waves). Wave w owns cols
// [32w, 32w+32) as 2 n-tiles; Ww frags (32 VGPR) register-resident.
#define XEPAD 264
__global__ __launch_bounds__(1024, 4) void wx_gemm(
    const int* __restrict__ x, const void* __restrict__ embv,
    const void* __restrict__ Wwv, const void* __restrict__ Wbv,
    const void* __restrict__ Ubv, unsigned char* __restrict__ ws)
{
    __shared__ __align__(16) __hip_bfloat16 xe_s[64][XEPAD];   // 33.8 KB
    __shared__ int flags_s;
    const int t = blockIdx.x, tid = threadIdx.x;
    if (tid == 0) flags_s = detect_flags(x, embv);
    __syncthreads();
    const bool f32w = (flags_s & 1) != 0;
    const bool x64  = (flags_s & 2) != 0;

    const int w = tid >> 6, lane = tid & 63, ln = lane & 15, q = lane >> 4;

    // loop-invariant: B-frags of Ww + bias, register-resident (32+2 regs)
    bf16x8 bf[2][8];
    float  bias[2];
#pragma unroll
    for (int tn = 0; tn < 2; ++tn) {
        long n = w * 32 + tn * 16 + ln;
        bias[tn] = ldf(Wbv, n, f32w) + ldf(Ubv, n, f32w);
#pragma unroll
        for (int kt = 0; kt < 8; ++kt) {
            bf16x8 v;
#pragma unroll
            for (int j = 0; j < 8; ++j)
                v[j] = (__bf16)ldf(Wwv, n * EMB + kt * 32 + q * 8 + j, f32w);
            bf[tn][kt] = v;
        }
    }

    for (int half = 0; half < 2; ++half) {
        // stage xe rows [64*half, 64*half+64): 16 thr/row, 4 floats x 4 passes
        {
            int row = tid >> 4, sub = tid & 15;
            int tok = get_tok(x, (half * 64 + row) * T_STEPS + t, x64);
#pragma unroll
            for (int i = 0; i < 4; ++i) {
                int col = sub * 4 + i * 64;
                float v0, v1, v2, v3;
                if (f32w) {
                    const float4 vv = *(const float4*)((const float*)embv
                                        + (long)tok * EMB + col);
                    v0 = vv.x; v1 = vv.y; v2 = vv.z; v3 = vv.w;
                } else {
                    const unsigned short* e = (const unsigned short*)embv
                                        + (long)tok * EMB + col;
                    v0 = bf2f(e[0]); v1 = bf2f(e[1]);
                    v2 = bf2f(e[2]); v3 = bf2f(e[3]);
                }
                __hip_bfloat16* d = &xe_s[row][col];
                d[0] = __float2bfloat16(v0); d[1] = __float2bfloat16(v1);
                d[2] = __float2bfloat16(v2); d[3] = __float2bfloat16(v3);
            }
        }
        __syncthreads();

#pragma unroll
        for (int bt = 0; bt < 4; ++bt) {
            f32x4 acc[2];
#pragma unroll
            for (int tn = 0; tn < 2; ++tn)
#pragma unroll
                for (int r = 0; r < 4; ++r) acc[tn][r] = bias[tn];
#pragma unroll
            for (int kt = 0; kt < 8; ++kt) {
                bf16x8 a = *(const bf16x8*)&xe_s[bt * 16 + ln][kt * 32 + q * 8];
#pragma unroll
                for (int tn = 0; tn < 2; ++tn)
                    acc[tn] = __builtin_amdgcn_mfma_f32_16x16x32_bf16(
                        a, bf[tn][kt], acc[tn], 0, 0, 0);
            }
            // C/D: batch row = half*64 + bt*16 + q*4 + r, col = w*32+tn*16+ln
#pragma unroll
            for (int tn = 0; tn < 2; ++tn)
#pragma unroll
                for (int r = 0; r < 4; ++r) {
                    long idx = ((long)t * 128 + half * 64 + bt * 16 + q * 4 + r) * 512
                             + w * 32 + tn * 16 + ln;
                    ((unsigned short*)ws)[idx] = f2bf(acc[tn][r]);
                }
        }
        __syncthreads();   // xe_s reads done before re-stage
    }
}

// =================== kernel 2: single-CU i8 scan ============================
// 8 blocks x 1024 thr (16 waves). Block g owns batches [16g,16g+16). Wave w
// owns cols [32w,32w+32) as 2 n-tiles. Uw i8 frags: uq[2][16] = 64 VGPR.
#define HQP 528
__global__ __launch_bounds__(1024, 4) void scan_i8(
    const void* __restrict__ Uwv, const void* __restrict__ Vwv,
    const void* __restrict__ Vbv, const int* __restrict__ x,
    const void* __restrict__ embv, const unsigned char* __restrict__ wsc,
    void* __restrict__ outv)
{
    __shared__ __align__(16) signed char hq[2][16][HQP];   // 16.9 KB ping-pong
    __shared__ float red[1024];
    __shared__ int flags_s;

    const int tid = threadIdx.x, g = blockIdx.x, b0 = g * 16;
    if (tid == 0) flags_s = detect_flags(x, embv);
    __syncthreads();
    const bool f32w = (flags_s & 1) != 0;

    const int w = tid >> 6, lane = tid & 63, ln = lane & 15, q = lane >> 4;

    // ---- su = max|Uw| (block-local, deterministic) -------------------------
    {
        float mx = 0.0f;
        if (f32w) {
            const float4* U4 = (const float4*)Uwv;
            for (int i = tid; i < 65536; i += 1024) {
                float4 v = U4[i];
                mx = fmaxf(mx, fmaxf(fmaxf(fabsf(v.x), fabsf(v.y)),
                                     fmaxf(fabsf(v.z), fabsf(v.w))));
            }
        } else {
            for (long i = tid; i < 262144; i += 1024)
                mx = fmaxf(mx, fabsf(ldf(Uwv, i, false)));
        }
        red[tid] = mx;
        __syncthreads();
        for (int s = 512; s > 0; s >>= 1) {
            if (tid < s) red[tid] = fmaxf(red[tid], red[tid + s]);
            __syncthreads();
        }
    }
    const float su = red[0];
    const float qs = 127.0f / su;
    const float sc = su / 16129.0f;          // su/(127*127)

    // ---- quantize Uw -> register-resident i8 B-frags (64 VGPR) -------------
    // B[k=kt*32+q*8+j][n=w*32+tn*16+ln] = Uw[n][k]
    unsigned long long uq[2][16];
#pragma unroll
    for (int tn = 0; tn < 2; ++tn) {
        long n = w * 32 + tn * 16 + ln;
#pragma unroll
        for (int kt = 0; kt < 16; ++kt) {
            unsigned long long pk = 0;
#pragma unroll
            for (int j = 0; j < 8; ++j) {
                float v = ldf(Uwv, n * HID + kt * 32 + q * 8 + j, f32w) * qs;
                int   qv = (int)__builtin_rintf(v);
                qv = qv > 127 ? 127 : (qv < -127 ? -127 : qv);
                pk |= ((unsigned long long)(unsigned char)(signed char)qv) << (8 * j);
            }
            uq[tn][kt] = pk;
        }
    }

    // h0 = 0
    for (int i = tid; i < 16 * HQP; i += 1024) ((signed char*)hq[0])[i] = 0;

    // wx(t=0): thread holds 8 wx values [tn][r]
    float wxc[8], wxn[8];
#pragma unroll
    for (int tn = 0; tn < 2; ++tn)
#pragma unroll
        for (int r = 0; r < 4; ++r) {
            long idx = ((long)0 * 128 + b0 + q * 4 + r) * 512 + w * 32 + tn * 16 + ln;
            wxc[tn * 4 + r] = bf2f(((const unsigned short*)wsc)[idx]);
        }
    __syncthreads();

    for (int t = 0; t < T_STEPS; ++t) {
        // prefetch wx(t+1)
        {
            int tn1 = (t + 1 < T_STEPS) ? (t + 1) : t;
#pragma unroll
            for (int tn = 0; tn < 2; ++tn)
#pragma unroll
                for (int r = 0; r < 4; ++r) {
                    long idx = ((long)tn1 * 128 + b0 + q * 4 + r) * 512
                             + w * 32 + tn * 16 + ln;
                    wxn[tn * 4 + r] = bf2f(((const unsigned short*)wsc)[idx]);
                }
        }

        i32x4 acc[2];
#pragma unroll
        for (int tn = 0; tn < 2; ++tn)
#pragma unroll
            for (int r = 0; r < 4; ++r) acc[tn][r] = 0;

        const signed char (*hr)[HQP] = hq[t & 1];
#pragma unroll
        for (int kt = 0; kt < 16; ++kt) {
            long long a = *(const long long*)&hr[ln][kt * 32 + q * 8];
#pragma unroll
            for (int tn = 0; tn < 2; ++tn)
                acc[tn] = __builtin_amdgcn_mfma_i32_16x16x32_i8(
                    a, (long long)uq[tn][kt], acc[tn], 0, 0, 0);
        }

        // fused tanh+quantize: q = clamp(rint(127 - 254*rcp(exp(2v)+1)))
        signed char (*hw)[HQP] = hq[(t + 1) & 1];
#pragma unroll
        for (int tn = 0; tn < 2; ++tn)
#pragma unroll
            for (int r = 0; r < 4; ++r) {
                float v  = wxc[tn * 4 + r] + (float)acc[tn][r] * sc;
                float e  = __expf(2.0f * v);                      // inf-safe
                float th = 127.0f - 254.0f * __builtin_amdgcn_rcpf(e + 1.0f);
                th = fminf(127.0f, fmaxf(-127.0f, th));
                hw[q * 4 + r][w * 32 + tn * 16 + ln] =
                    (signed char)(int)__builtin_rintf(th);
            }
#pragma unroll
        for (int i = 0; i < 8; ++i) wxc[i] = wxn[i];
        __syncthreads();   // h' sealed; next step reads it
    }

    // logits = hT @ Vw^T + Vb ; final h in hq[0] (T even)
    if (tid < 512) {
        int b = tid >> 5, o = (tid >> 4) & 1, kp = tid & 15;
        float s = 0.0f;
#pragma unroll 4
        for (int j = 0; j < 32; ++j) {
            int k = kp * 32 + j;
            s += (float)hq[0][b][k] * (1.0f / 127.0f) * ldf(Vwv, (long)o * HID + k, f32w);
        }
        s += __shfl_xor(s, 1);
        s += __shfl_xor(s, 2);
        s += __shfl_xor(s, 4);
        s += __shfl_xor(s, 8);
        if (kp == 0)
            stf(outv, (long)(b0 + b) * 2 + o, s + ldf(Vbv, o, f32w), f32w);
    }
}

// =================== fallback: r7 MALL-exchange scan (proven) ===============
#define XPAD 264
#define HPAD 528
#define BPG  4
#define R7_WS_H   4096
#define R7_WS_NEED (4096 + 2 * 8 * 16 * 256 * 4)

__device__ inline void load_xe(const void* emb, long base, bool f32,
                               bf16x8* a, bf16x8* b) {
    if (f32) {
        const float* p = (const float*)emb + base;
        bf16x8 va, vb;
#pragma unroll
        for (int j = 0; j < 8; ++j) va[j] = (__bf16)p[j];
#pragma unroll
        for (int j = 0; j < 8; ++j) vb[j] = (__bf16)p[8 + j];
        *a = va; *b = vb;
    } else {
        const bf16x8* p = (const bf16x8*)((const unsigned short*)emb + base);
        *a = p[0]; *b = p[1];
    }
}

__global__ __launch_bounds__(256, 1) void scan_mfma_fb(
    const int* __restrict__ x, const void* __restrict__ embv,
    const void* __restrict__ Wwv, const void* __restrict__ Wbv,
    const void* __restrict__ Uwv, const void* __restrict__ Ubv,
    const void* __restrict__ Vwv, const void* __restrict__ Vbv,
    unsigned char* __restrict__ ws, void* __restrict__ outv)
{
    __shared__ __align__(16) __hip_bfloat16 xe_s[16][XPAD];
    __shared__ __align__(16) __hip_bfloat16 hbuf[2][16][HPAD];
    __shared__ int flags_s;

    const int tid = threadIdx.x;
    const int g   = blockIdx.x >> 2;
    const int cg  = blockIdx.x & 3;
    const int b0  = g * 16;

    if (tid == 0) flags_s = detect_flags(x, embv);
    __syncthreads();
    const bool f32w = (flags_s & 1) != 0;
    const bool x64  = (flags_s & 2) != 0;

    const int w = tid >> 6, lane = tid & 63, ln = lane & 15, q = lane >> 4;
    const int n0 = cg * 128 + w * 32 + ln;

    for (int i = tid; i < 2 * 16 * HPAD; i += 256)
        ((__hip_bfloat16*)hbuf)[i] = __float2bfloat16(0.0f);

    bf16x8 ufr[2][16], wfr[2][8];
#pragma unroll
    for (int half = 0; half < 2; ++half) {
        const long n = n0 + half * 16;
#pragma unroll
        for (int kt = 0; kt < 16; ++kt) {
            bf16x8 v;
#pragma unroll
            for (int j = 0; j < 8; ++j)
                v[j] = (__bf16)ldf(Uwv, n * HID + kt * 32 + q * 8 + j, f32w);
            ufr[half][kt] = v;
        }
#pragma unroll
        for (int kt = 0; kt < 8; ++kt) {
            bf16x8 v;
#pragma unroll
            for (int j = 0; j < 8; ++j)
                v[j] = (__bf16)ldf(Wwv, n * EMB + kt * 32 + q * 8 + j, f32w);
            wfr[half][kt] = v;
        }
    }
    const float bias0 = ldf(Wbv, n0, f32w)      + ldf(Ubv, n0, f32w);
    const float bias1 = ldf(Wbv, n0 + 16, f32w) + ldf(Ubv, n0 + 16, f32w);

    const int xr = tid >> 4, xc = (tid & 15) * 16;
    {
        int tok = get_tok(x, (b0 + xr) * T_STEPS + 0, x64);
        bf16x8 xa, xb;
        load_xe(embv, (long)tok * EMB + xc, f32w, &xa, &xb);
        *(bf16x8*)&xe_s[xr][xc]     = xa;
        *(bf16x8*)&xe_s[xr][xc + 8] = xb;
    }
    __syncthreads();

    unsigned*           hg32 = (unsigned*)(ws + R7_WS_H);
    unsigned long long* hg64 = (unsigned long long*)(ws + R7_WS_H);
    int*                cnt  = (int*)(void*)ws + g * 32;

    for (int t = 0; t < T_STEPS; ++t) {
        bf16x8 nxa, nxb;
        const bool have_next = (t + 1 < T_STEPS);
        if (have_next) {
            int tok = get_tok(x, (b0 + xr) * T_STEPS + (t + 1), x64);
            load_xe(embv, (long)tok * EMB + xc, f32w, &nxa, &nxb);
        }

        f32x4 acc0, acc1;
#pragma unroll
        for (int r = 0; r < 4; ++r) { acc0[r] = bias0; acc1[r] = bias1; }
#pragma unroll
        for (int kt = 0; kt < 8; ++kt) {
            bf16x8 a = *(const bf16x8*)&xe_s[ln][kt * 32 + q * 8];
            acc0 = __builtin_amdgcn_mfma_f32_16x16x32_bf16(a, wfr[0][kt], acc0, 0, 0, 0);
            acc1 = __builtin_amdgcn_mfma_f32_16x16x32_bf16(a, wfr[1][kt], acc1, 0, 0, 0);
        }
        const __hip_bfloat16 (*hr)[HPAD] = hbuf[t & 1];
#pragma unroll
        for (int kt = 0; kt < 16; ++kt) {
            bf16x8 a = *(const bf16x8*)&hr[ln][kt * 32 + q * 8];
            acc0 = __builtin_amdgcn_mfma_f32_16x16x32_bf16(a, ufr[0][kt], acc0, 0, 0, 0);
            acc1 = __builtin_amdgcn_mfma_f32_16x16x32_bf16(a, ufr[1][kt], acc1, 0, 0, 0);
        }

        const int nb = (t + 1) & 1;
        {
            unsigned* dst = hg32 + (size_t)(nb * 8 + g) * 4096 + cg * 64 + w * 16 + ln;
#pragma unroll
            for (int r = 0; r < 4; ++r) {
                unsigned word = (unsigned)f2bf(tanh_f(acc0[r]))
                              | ((unsigned)f2bf(tanh_f(acc1[r])) << 16);
                __hip_atomic_store(dst + (size_t)(q * 4 + r) * 256, word,
                                   __ATOMIC_RELAXED, __HIP_MEMORY_SCOPE_AGENT);
            }
        }
        asm volatile("s_waitcnt vmcnt(0)" ::: "memory");
        __syncthreads();

        if (have_next) {
            *(bf16x8*)&xe_s[xr][xc]     = nxa;
            *(bf16x8*)&xe_s[xr][xc + 8] = nxb;
        }

        if (tid == 0) {
            __hip_atomic_fetch_add(cnt, 1, __ATOMIC_RELAXED,
                                   __HIP_MEMORY_SCOPE_AGENT);
            const int target = BPG * (t + 1);
            while (__hip_atomic_load(cnt, __ATOMIC_RELAXED,
                                     __HIP_MEMORY_SCOPE_AGENT) < target)
                __builtin_amdgcn_s_sleep(1);
        }
        __syncthreads();

        {
            const unsigned long long* src = hg64 + (size_t)(nb * 8 + g) * 2048;
#pragma unroll
            for (int m = tid; m < 2048; m += 256) {
                unsigned long long v = __hip_atomic_load(
                    src + m, __ATOMIC_RELAXED, __HIP_MEMORY_SCOPE_AGENT);
                int row = m >> 7, p = m & 127;
                int j0  = 2 * p;
                int cgp = j0 >> 6, wv = (j0 >> 4) & 3, l0 = j0 & 15;
                int colA = cgp * 128 + wv * 32 + l0;
                unsigned w0 = (unsigned)v, w1 = (unsigned)(v >> 32);
                unsigned lo = (w0 & 0xffffu) | (w1 << 16);
                unsigned hi = (w0 >> 16) | (w1 & 0xffff0000u);
                *(unsigned*)&hbuf[nb][row][colA]      = lo;
                *(unsigned*)&hbuf[nb][row][colA + 16] = hi;
            }
        }
        __syncthreads();
    }

    if (cg == 0) {
        int b = tid >> 4, rem = tid & 15, o = rem >> 3, kp = rem & 7;
        float s = 0.0f;
#pragma unroll 4
        for (int j = 0; j < 64; ++j) {
            int k = kp * 64 + j;
            s += __bfloat162float(hbuf[0][b][k]) * ldf(Vwv, (long)o * HID + k, f32w);
        }
        s += __shfl_xor(s, 1);
        s += __shfl_xor(s, 2);
        s += __shfl_xor(s, 4);
        if (kp == 0)
            stf(outv, (long)(b0 + b) * 2 + o, s + ldf(Vbv, o, f32w), f32w);
    }
}

// =================== fixup: NaN net + forced-anchor fallback ================
#define B_PER 2
__global__ __launch_bounds__(512) void fixup(
    const int* __restrict__ x, const void* __restrict__ emb,
    const void* __restrict__ Ww, const void* __restrict__ Wb,
    const void* __restrict__ Uw, const void* __restrict__ Ub,
    const void* __restrict__ Vw, const void* __restrict__ Vb,
    void* __restrict__ out, int force)
{
    __shared__ float h_s[2][B_PER][HID];
    __shared__ float xe_sf[B_PER][EMB];
    __shared__ int   flags_s, bad_s;

    const int tid = threadIdx.x;
    const int b0  = blockIdx.x * B_PER;

    if (tid == 0) {
        int fl = detect_flags(x, emb);
        flags_s = fl;
        int bad = force;
        if (!force) {
            bool f32o = (fl & 1) != 0;
            for (int i = 0; i < 2 * B_PER; ++i) {
                int oi = b0 * 2 + i;
                if (f32o) {
                    float v = ((const float*)out)[oi];
                    bad |= (v != v);
                } else {
                    unsigned short u = ((const unsigned short*)out)[oi];
                    bad |= (((u & 0x7F80u) == 0x7F80u) && ((u & 0x7Fu) != 0));
                }
            }
        }
        bad_s = bad;
    }
    __syncthreads();
    if (!bad_s) return;

    const bool f32w = (flags_s & 1) != 0;
    const bool x64  = (flags_s & 2) != 0;
    const int n = tid;
    const float bias = ldf(Wb, n, f32w) + ldf(Ub, n, f32w);

    for (int b = 0; b < B_PER; ++b) h_s[0][b][n] = 0.0f;

    for (int t = 0; t < T_STEPS; ++t) {
        {
            int b = tid >> 8, c = tid & 255;
            int tok = get_tok(x, (b0 + b) * T_STEPS + t, x64);
            xe_sf[b][c] = ldf(emb, (long)tok * EMB + c, f32w);
        }
        __syncthreads();

        float acc0 = bias, acc1 = bias;
        const long wrow = (long)n * EMB;
#pragma unroll 8
        for (int k = 0; k < EMB; ++k) {
            float wv = ldf(Ww, wrow + k, f32w);
            acc0 += xe_sf[0][k] * wv;
            acc1 += xe_sf[1][k] * wv;
        }
        const long urow = (long)n * HID;
        const float* hc0 = h_s[t & 1][0];
        const float* hc1 = h_s[t & 1][1];
#pragma unroll 8
        for (int k = 0; k < HID; ++k) {
            float uv = ldf(Uw, urow + k, f32w);
            acc0 += hc0[k] * uv;
            acc1 += hc1[k] * uv;
        }
        h_s[(t + 1) & 1][0][n] = tanhf(acc0);
        h_s[(t + 1) & 1][1][n] = tanhf(acc1);
        __syncthreads();
    }

    if (tid < 2 * B_PER) {
        int b = tid >> 1, o = tid & 1;
        float s = ldf(Vb, o, f32w);
        for (int k = 0; k < HID; ++k)
            s += h_s[0][b][k] * ldf(Vw, (long)o * HID + k, f32w);
        stf(out, (b0 + b) * 2 + o, s, f32w);
    }
}

extern "C" void kernel_launch(void* const* d_in, const int* in_sizes, int n_in,
                              void* d_out, int out_size, void* d_ws, size_t ws_size,
                              hipStream_t stream) {
    const int* x = (const int*)d_in[0];
    const size_t WX16 = (size_t)T_STEPS * 128 * 512 * 2;   // 64 MB bf16
    if (ws_size >= WX16) {
        wx_gemm<<<512, 1024, 0, stream>>>(
            x, d_in[1], d_in[2], d_in[3], d_in[5], (unsigned char*)d_ws);
        scan_i8<<<8, 1024, 0, stream>>>(
            d_in[4], d_in[6], d_in[7], x, d_in[1],
            (const unsigned char*)d_ws, d_out);
        fixup<<<64, 512, 0, stream>>>(
            x, d_in[1], d_in[2], d_in[3], d_in[4], d_in[5], d_in[6], d_in[7],
            d_out, 0);
    } else if (ws_size >= (size_t)R7_WS_NEED) {
        hipMemsetAsync(d_ws, 0, 4096, stream);
        scan_mfma_fb<<<32, 256, 0, stream>>>(
            x, d_in[1], d_in[2], d_in[3], d_in[4], d_in[5], d_in[6], d_in[7],
            (unsigned char*)d_ws, d_out);
        fixup<<<64, 512, 0, stream>>>(
            x, d_in[1], d_in[2], d_in[3], d_in[4], d_in[5], d_in[6], d_in[7],
            d_out, 0);
    } else {
        fixup<<<64, 512, 0, stream>>>(
            x, d_in[1], d_in[2], d_in[3], d_in[4], d_in[5], d_in[6], d_in[7],
            d_out, 1);
    }
}

// Round 10
// 1227.880 us; speedup vs baseline: 71.1140x; 1.0357x over previous
//
#include <hip/hip_runtime.h>
#include <hip/hip_bf16.h>
#include <math.h>

// Elman RNN. VOCAB=50257, EMB=256, HID=512, OUT=2, B=128, T=512.
// R10: epilogue-optimized i8 scan. r9 counters: VALUBusy>MfmaUtil on active
// CUs; tanh+quantize (exp+rcp, ~50cyc/elem) was the largest per-step term.
//  - Pade(5,4) tanh (continued-fraction truncation, err<1e-3, clamp 3.5),
//    127 folded into numerator, magic-number byte rounding: no exp, no cvt.
//  - wx stored in scan-fragment order -> one dwordx4 load/thread/step.
//  - h stored k-permuted (c' = w*32+ln*2+tn) -> 4x ds_write_b16 instead of
//    8x ds_write_b8; Uw fragments quantized with the same within-32-block
//    permutation so MFMA results are identical.
//  - __launch_bounds__(1024) only (grid=8 blocks; extra occupancy useless).
// Fallbacks: r7 MALL scan (ws small), forced anchor, NaN-net fixup.

#define VOCAB   50257
#define T_STEPS 512
#define HID     512
#define EMB     256

typedef __bf16 bf16x8 __attribute__((ext_vector_type(8)));
typedef float  f32x4  __attribute__((ext_vector_type(4)));
typedef int    i32x4  __attribute__((ext_vector_type(4)));

__device__ inline float ldf(const void* p, long i, bool f32) {
    if (f32) return ((const float*)p)[i];
    unsigned bits = ((unsigned)((const unsigned short*)p)[i]) << 16;
    return __uint_as_float(bits);
}
__device__ inline void stf(void* p, long i, float v, bool f32) {
    if (f32) { ((float*)p)[i] = v; return; }
    unsigned b = __float_as_uint(v);
    unsigned r = (b + 0x7fffu + ((b >> 16) & 1u)) >> 16;   // RNE bf16
    ((unsigned short*)p)[i] = (unsigned short)r;
}
__device__ inline unsigned short f2bf(float v) {
    unsigned b = __float_as_uint(v);
    return (unsigned short)((b + 0x7fffu + ((b >> 16) & 1u)) >> 16);
}
__device__ inline float bf2f(unsigned short u) {
    return __uint_as_float(((unsigned)u) << 16);
}
__device__ inline int get_tok(const int* x, int idx, bool x64) {
    unsigned u = (unsigned)(x64 ? x[2 * idx] : x[idx]);
    return (u < (unsigned)VOCAB) ? (int)u : 0;
}
__device__ inline int detect_flags(const int* x, const void* emb) {
    int allz = 1;   // floats f32? (bf16-view of f32 emb row0 stays zero)
    const unsigned short* e16 = (const unsigned short*)emb;
    for (int i = 256; i < 320; ++i) allz &= (e16[i] == 0);
    int x64 = 1;    // x int64?
    for (int j = 1; j < 16; j += 2) x64 &= (x[j] == 0);
    return allz | (x64 << 1);
}
__device__ inline float tanh_f(float x) {
    float ax = fabsf(x);
    float e  = __expf(-2.0f * ax);
    float t  = (1.0f - e) * __builtin_amdgcn_rcpf(1.0f + e);
    return copysignf(t, x);
}
// q-byte = low8( rne( 127*tanh_pade(v) + 1.5*2^23 ) ); Pade(5,4) of tanh,
// clamp |v|<=3.5 (err<=9e-4; 127*0.99911 rounds to 127 like exact tanh).
__device__ inline unsigned tq(float v) {
    float x = fminf(3.5f, fmaxf(-3.5f, v));
    float s = x * x;
    float num = x * fmaf(s, fmaf(s, 127.0f, 13335.0f), 120015.0f);  // 127*(945+105s+s^2)
    float den = fmaf(s, fmaf(s, 15.0f, 420.0f), 945.0f);
    float f = fmaf(num, __builtin_amdgcn_rcpf(den), 12582912.0f);
    return __float_as_uint(f) & 0xffu;
}

// =================== kernel 1: wx = xe@Ww^T + Wb + Ub (fragment order) ======
// grid 512 (one block per t) x 1024 thr. Output: for batch-group g=half*4+bt,
// thread tid's 8 values stored contiguously at ws[(((t*8+g)*1024+tid)*8)*2 B].
#define XEPAD 264
__global__ __launch_bounds__(1024) void wx_gemm(
    const int* __restrict__ x, const void* __restrict__ embv,
    const void* __restrict__ Wwv, const void* __restrict__ Wbv,
    const void* __restrict__ Ubv, unsigned char* __restrict__ ws)
{
    __shared__ __align__(16) __hip_bfloat16 xe_s[64][XEPAD];   // 33.8 KB
    __shared__ int flags_s;
    const int t = blockIdx.x, tid = threadIdx.x;
    if (tid == 0) flags_s = detect_flags(x, embv);
    __syncthreads();
    const bool f32w = (flags_s & 1) != 0;
    const bool x64  = (flags_s & 2) != 0;

    const int w = tid >> 6, lane = tid & 63, ln = lane & 15, q = lane >> 4;

    bf16x8 bf[2][8];
    float  bias[2];
#pragma unroll
    for (int tn = 0; tn < 2; ++tn) {
        long n = w * 32 + tn * 16 + ln;
        bias[tn] = ldf(Wbv, n, f32w) + ldf(Ubv, n, f32w);
#pragma unroll
        for (int kt = 0; kt < 8; ++kt) {
            bf16x8 v;
#pragma unroll
            for (int j = 0; j < 8; ++j)
                v[j] = (__bf16)ldf(Wwv, n * EMB + kt * 32 + q * 8 + j, f32w);
            bf[tn][kt] = v;
        }
    }

    for (int half = 0; half < 2; ++half) {
        {
            int row = tid >> 4, sub = tid & 15;
            int tok = get_tok(x, (half * 64 + row) * T_STEPS + t, x64);
#pragma unroll
            for (int i = 0; i < 4; ++i) {
                int col = sub * 4 + i * 64;
                float v0, v1, v2, v3;
                if (f32w) {
                    const float4 vv = *(const float4*)((const float*)embv
                                        + (long)tok * EMB + col);
                    v0 = vv.x; v1 = vv.y; v2 = vv.z; v3 = vv.w;
                } else {
                    const unsigned short* e = (const unsigned short*)embv
                                        + (long)tok * EMB + col;
                    v0 = bf2f(e[0]); v1 = bf2f(e[1]);
                    v2 = bf2f(e[2]); v3 = bf2f(e[3]);
                }
                __hip_bfloat16* d = &xe_s[row][col];
                d[0] = __float2bfloat16(v0); d[1] = __float2bfloat16(v1);
                d[2] = __float2bfloat16(v2); d[3] = __float2bfloat16(v3);
            }
        }
        __syncthreads();

#pragma unroll
        for (int bt = 0; bt < 4; ++bt) {
            f32x4 acc[2];
#pragma unroll
            for (int tn = 0; tn < 2; ++tn)
#pragma unroll
                for (int r = 0; r < 4; ++r) acc[tn][r] = bias[tn];
#pragma unroll
            for (int kt = 0; kt < 8; ++kt) {
                bf16x8 a = *(const bf16x8*)&xe_s[bt * 16 + ln][kt * 32 + q * 8];
#pragma unroll
                for (int tn = 0; tn < 2; ++tn)
                    acc[tn] = __builtin_amdgcn_mfma_f32_16x16x32_bf16(
                        a, bf[tn][kt], acc[tn], 0, 0, 0);
            }
            // fragment-order store: g = half*4+bt; 8 bf16 contiguous per thread
            {
                int g = half * 4 + bt;
                unsigned short o8[8];
#pragma unroll
                for (int tn = 0; tn < 2; ++tn)
#pragma unroll
                    for (int r = 0; r < 4; ++r)
                        o8[tn * 4 + r] = f2bf(acc[tn][r]);
                long ofs = (((long)t * 8 + g) * 1024 + tid) * 16;
                *(uint4*)(ws + ofs) = *(const uint4*)o8;
            }
        }
        __syncthreads();
    }
}

// =================== kernel 2: single-CU i8 scan ============================
// 8 blocks x 1024 thr (16 waves). Wave w owns logical cols {w*32+tn*16+ln}.
// h stored k-permuted in LDS: physical c' = w*32 + ln*2 + tn.
#define HQP 528
__global__ __launch_bounds__(1024) void scan_i8(
    const void* __restrict__ Uwv, const void* __restrict__ Vwv,
    const void* __restrict__ Vbv, const int* __restrict__ x,
    const void* __restrict__ embv, const unsigned char* __restrict__ wsc,
    void* __restrict__ outv)
{
    __shared__ __align__(16) signed char hq[2][16][HQP];   // 16.9 KB ping-pong
    __shared__ float red[1024];
    __shared__ int flags_s;

    const int tid = threadIdx.x, g = blockIdx.x, b0 = g * 16;
    if (tid == 0) flags_s = detect_flags(x, embv);
    __syncthreads();
    const bool f32w = (flags_s & 1) != 0;

    const int w = tid >> 6, lane = tid & 63, ln = lane & 15, q = lane >> 4;

    // ---- su = max|Uw| (block-local, deterministic) -------------------------
    {
        float mx = 0.0f;
        if (f32w) {
            const float4* U4 = (const float4*)Uwv;
            for (int i = tid; i < 65536; i += 1024) {
                float4 v = U4[i];
                mx = fmaxf(mx, fmaxf(fmaxf(fabsf(v.x), fabsf(v.y)),
                                     fmaxf(fabsf(v.z), fabsf(v.w))));
            }
        } else {
            for (long i = tid; i < 262144; i += 1024)
                mx = fmaxf(mx, fabsf(ldf(Uwv, i, false)));
        }
        red[tid] = mx;
        __syncthreads();
        for (int s = 512; s > 0; s >>= 1) {
            if (tid < s) red[tid] = fmaxf(red[tid], red[tid + s]);
            __syncthreads();
        }
    }
    const float su = red[0];
    const float qs = 127.0f / su;
    const float sc = su / 16129.0f;          // su/(127*127)

    // ---- quantize Uw -> register-resident i8 B-frags (64 VGPR) -------------
    // physical byte j of frag (tn,kt,q) = Uw[n][kt*32 + kl], kl = within-32
    // logical index of physical kp=q*8+j under c'=perm: kl=((kp&1)<<4)|(kp>>1)
    unsigned long long uq[2][16];
#pragma unroll
    for (int tn = 0; tn < 2; ++tn) {
        long n = w * 32 + tn * 16 + ln;
#pragma unroll
        for (int kt = 0; kt < 16; ++kt) {
            unsigned long long pk = 0;
#pragma unroll
            for (int j = 0; j < 8; ++j) {
                int kp = q * 8 + j;
                int kl = ((kp & 1) << 4) | (kp >> 1);
                float v = ldf(Uwv, n * HID + kt * 32 + kl, f32w) * qs;
                int   qv = (int)__builtin_rintf(v);
                qv = qv > 127 ? 127 : (qv < -127 ? -127 : qv);
                pk |= ((unsigned long long)(unsigned char)(signed char)qv) << (8 * j);
            }
            uq[tn][kt] = pk;
        }
    }

    // h0 = 0
    for (int i = tid; i < 16 * HQP; i += 1024) ((signed char*)hq[0])[i] = 0;
    __syncthreads();

    const unsigned char* wxp = wsc + ((long)g * 1024 + tid) * 16;
    const long wx_step = 8L * 1024 * 16;

    for (int t = 0; t < T_STEPS; ++t) {
        // wx(t): one coalesced 16B load; consumed only at the epilogue
        uint4 wv = *(const uint4*)(wxp + (long)t * wx_step);

        i32x4 acc[2];
#pragma unroll
        for (int tn = 0; tn < 2; ++tn)
#pragma unroll
            for (int r = 0; r < 4; ++r) acc[tn][r] = 0;

        const signed char (*hr)[HQP] = hq[t & 1];
#pragma unroll
        for (int ktb = 0; ktb < 2; ++ktb) {
            long long afr[8];
#pragma unroll
            for (int k = 0; k < 8; ++k)
                afr[k] = *(const long long*)&hr[ln][(ktb * 8 + k) * 32 + q * 8];
#pragma unroll
            for (int k = 0; k < 8; ++k) {
                acc[0] = __builtin_amdgcn_mfma_i32_16x16x32_i8(
                    afr[k], (long long)uq[0][ktb * 8 + k], acc[0], 0, 0, 0);
                acc[1] = __builtin_amdgcn_mfma_i32_16x16x32_i8(
                    afr[k], (long long)uq[1][ktb * 8 + k], acc[1], 0, 0, 0);
            }
        }

        // epilogue: unpack wx (bf16 pairs), Pade-tanh-quantize, paired b16 write
        float wx0[4], wx1[4];
        wx0[0] = __uint_as_float(wv.x << 16); wx0[1] = __uint_as_float(wv.x & 0xffff0000u);
        wx0[2] = __uint_as_float(wv.y << 16); wx0[3] = __uint_as_float(wv.y & 0xffff0000u);
        wx1[0] = __uint_as_float(wv.z << 16); wx1[1] = __uint_as_float(wv.z & 0xffff0000u);
        wx1[2] = __uint_as_float(wv.w << 16); wx1[3] = __uint_as_float(wv.w & 0xffff0000u);

        signed char (*hw)[HQP] = hq[(t + 1) & 1];
#pragma unroll
        for (int r = 0; r < 4; ++r) {
            unsigned c0 = tq(fmaf((float)acc[0][r], sc, wx0[r]));
            unsigned c1 = tq(fmaf((float)acc[1][r], sc, wx1[r]));
            *(unsigned short*)&hw[q * 4 + r][w * 32 + ln * 2] =
                (unsigned short)(c0 | (c1 << 8));
        }
        __syncthreads();   // h' sealed; next step reads it
    }

    // logits = hT @ Vw^T + Vb ; final h in hq[0] (T even); k' is permuted
    if (tid < 512) {
        int b = tid >> 5, o = (tid >> 4) & 1, kp = tid & 15;
        float s = 0.0f;
#pragma unroll 4
        for (int j = 0; j < 32; ++j) {
            int kph = kp * 32 + j;                               // physical
            int kl = (kph & ~31) | ((kph & 1) << 4) | ((kph >> 1) & 15);
            s += (float)hq[0][b][kph] * (1.0f / 127.0f)
               * ldf(Vwv, (long)o * HID + kl, f32w);
        }
        s += __shfl_xor(s, 1);
        s += __shfl_xor(s, 2);
        s += __shfl_xor(s, 4);
        s += __shfl_xor(s, 8);
        if (kp == 0)
            stf(outv, (long)(b0 + b) * 2 + o, s + ldf(Vbv, o, f32w), f32w);
    }
}

// =================== fallback: r7 MALL-exchange scan (proven) ===============
#define XPAD 264
#define HPAD 528
#define BPG  4
#define R7_WS_H   4096
#define R7_WS_NEED (4096 + 2 * 8 * 16 * 256 * 4)

__device__ inline void load_xe(const void* emb, long base, bool f32,
                               bf16x8* a, bf16x8* b) {
    if (f32) {
        const float* p = (const float*)emb + base;
        bf16x8 va, vb;
#pragma unroll
        for (int j = 0; j < 8; ++j) va[j] = (__bf16)p[j];
#pragma unroll
        for (int j = 0; j < 8; ++j) vb[j] = (__bf16)p[8 + j];
        *a = va; *b = vb;
    } else {
        const bf16x8* p = (const bf16x8*)((const unsigned short*)emb + base);
        *a = p[0]; *b = p[1];
    }
}

__global__ __launch_bounds__(256, 1) void scan_mfma_fb(
    const int* __restrict__ x, const void* __restrict__ embv,
    const void* __restrict__ Wwv, const void* __restrict__ Wbv,
    const void* __restrict__ Uwv, const void* __restrict__ Ubv,
    const void* __restrict__ Vwv, const void* __restrict__ Vbv,
    unsigned char* __restrict__ ws, void* __restrict__ outv)
{
    __shared__ __align__(16) __hip_bfloat16 xe_s[16][XPAD];
    __shared__ __align__(16) __hip_bfloat16 hbuf[2][16][HPAD];
    __shared__ int flags_s;

    const int tid = threadIdx.x;
    const int g   = blockIdx.x >> 2;
    const int cg  = blockIdx.x & 3;
    const int b0  = g * 16;

    if (tid == 0) flags_s = detect_flags(x, embv);
    __syncthreads();
    const bool f32w = (flags_s & 1) != 0;
    const bool x64  = (flags_s & 2) != 0;

    const int w = tid >> 6, lane = tid & 63, ln = lane & 15, q = lane >> 4;
    const int n0 = cg * 128 + w * 32 + ln;

    for (int i = tid; i < 2 * 16 * HPAD; i += 256)
        ((__hip_bfloat16*)hbuf)[i] = __float2bfloat16(0.0f);

    bf16x8 ufr[2][16], wfr[2][8];
#pragma unroll
    for (int half = 0; half < 2; ++half) {
        const long n = n0 + half * 16;
#pragma unroll
        for (int kt = 0; kt < 16; ++kt) {
            bf16x8 v;
#pragma unroll
            for (int j = 0; j < 8; ++j)
                v[j] = (__bf16)ldf(Uwv, n * HID + kt * 32 + q * 8 + j, f32w);
            ufr[half][kt] = v;
        }
#pragma unroll
        for (int kt = 0; kt < 8; ++kt) {
            bf16x8 v;
#pragma unroll
            for (int j = 0; j < 8; ++j)
                v[j] = (__bf16)ldf(Wwv, n * EMB + kt * 32 + q * 8 + j, f32w);
            wfr[half][kt] = v;
        }
    }
    const float bias0 = ldf(Wbv, n0, f32w)      + ldf(Ubv, n0, f32w);
    const float bias1 = ldf(Wbv, n0 + 16, f32w) + ldf(Ubv, n0 + 16, f32w);

    const int xr = tid >> 4, xc = (tid & 15) * 16;
    {
        int tok = get_tok(x, (b0 + xr) * T_STEPS + 0, x64);
        bf16x8 xa, xb;
        load_xe(embv, (long)tok * EMB + xc, f32w, &xa, &xb);
        *(bf16x8*)&xe_s[xr][xc]     = xa;
        *(bf16x8*)&xe_s[xr][xc + 8] = xb;
    }
    __syncthreads();

    unsigned*           hg32 = (unsigned*)(ws + R7_WS_H);
    unsigned long long* hg64 = (unsigned long long*)(ws + R7_WS_H);
    int*                cnt  = (int*)(void*)ws + g * 32;

    for (int t = 0; t < T_STEPS; ++t) {
        bf16x8 nxa, nxb;
        const bool have_next = (t + 1 < T_STEPS);
        if (have_next) {
            int tok = get_tok(x, (b0 + xr) * T_STEPS + (t + 1), x64);
            load_xe(embv, (long)tok * EMB + xc, f32w, &nxa, &nxb);
        }

        f32x4 acc0, acc1;
#pragma unroll
        for (int r = 0; r < 4; ++r) { acc0[r] = bias0; acc1[r] = bias1; }
#pragma unroll
        for (int kt = 0; kt < 8; ++kt) {
            bf16x8 a = *(const bf16x8*)&xe_s[ln][kt * 32 + q * 8];
            acc0 = __builtin_amdgcn_mfma_f32_16x16x32_bf16(a, wfr[0][kt], acc0, 0, 0, 0);
            acc1 = __builtin_amdgcn_mfma_f32_16x16x32_bf16(a, wfr[1][kt], acc1, 0, 0, 0);
        }
        const __hip_bfloat16 (*hr)[HPAD] = hbuf[t & 1];
#pragma unroll
        for (int kt = 0; kt < 16; ++kt) {
            bf16x8 a = *(const bf16x8*)&hr[ln][kt * 32 + q * 8];
            acc0 = __builtin_amdgcn_mfma_f32_16x16x32_bf16(a, ufr[0][kt], acc0, 0, 0, 0);
            acc1 = __builtin_amdgcn_mfma_f32_16x16x32_bf16(a, ufr[1][kt], acc1, 0, 0, 0);
        }

        const int nb = (t + 1) & 1;
        {
            unsigned* dst = hg32 + (size_t)(nb * 8 + g) * 4096 + cg * 64 + w * 16 + ln;
#pragma unroll
            for (int r = 0; r < 4; ++r) {
                unsigned word = (unsigned)f2bf(tanh_f(acc0[r]))
                              | ((unsigned)f2bf(tanh_f(acc1[r])) << 16);
                __hip_atomic_store(dst + (size_t)(q * 4 + r) * 256, word,
                                   __ATOMIC_RELAXED, __HIP_MEMORY_SCOPE_AGENT);
            }
        }
        asm volatile("s_waitcnt vmcnt(0)" ::: "memory");
        __syncthreads();

        if (have_next) {
            *(bf16x8*)&xe_s[xr][xc]     = nxa;
            *(bf16x8*)&xe_s[xr][xc + 8] = nxb;
        }

        if (tid == 0) {
            __hip_atomic_fetch_add(cnt, 1, __ATOMIC_RELAXED,
                                   __HIP_MEMORY_SCOPE_AGENT);
            const int target = BPG * (t + 1);
            while (__hip_atomic_load(cnt, __ATOMIC_RELAXED,
                                     __HIP_MEMORY_SCOPE_AGENT) < target)
                __builtin_amdgcn_s_sleep(1);
        }
        __syncthreads();

        {
            const unsigned long long* src = hg64 + (size_t)(nb * 8 + g) * 2048;
#pragma unroll
            for (int m = tid; m < 2048; m += 256) {
                unsigned long long v = __hip_atomic_load(
                    src + m, __ATOMIC_RELAXED, __HIP_MEMORY_SCOPE_AGENT);
                int row = m >> 7, p = m & 127;
                int j0  = 2 * p;
                int cgp = j0 >> 6, wv = (j0 >> 4) & 3, l0 = j0 & 15;
                int colA = cgp * 128 + wv * 32 + l0;
                unsigned w0 = (unsigned)v, w1 = (unsigned)(v >> 32);
                unsigned lo = (w0 & 0xffffu) | (w1 << 16);
                unsigned hi = (w0 >> 16) | (w1 & 0xffff0000u);
                *(unsigned*)&hbuf[nb][row][colA]      = lo;
                *(unsigned*)&hbuf[nb][row][colA + 16] = hi;
            }
        }
        __syncthreads();
    }

    if (cg == 0) {
        int b = tid >> 4, rem = tid & 15, o = rem >> 3, kp = rem & 7;
        float s = 0.0f;
#pragma unroll 4
        for (int j = 0; j < 64; ++j) {
            int k = kp * 64 + j;
            s += __bfloat162float(hbuf[0][b][k]) * ldf(Vwv, (long)o * HID + k, f32w);
        }
        s += __shfl_xor(s, 1);
        s += __shfl_xor(s, 2);
        s += __shfl_xor(s, 4);
        if (kp == 0)
            stf(outv, (long)(b0 + b) * 2 + o, s + ldf(Vbv, o, f32w), f32w);
    }
}

// =================== fixup: NaN net + forced-anchor fallback ================
#define B_PER 2
__global__ __launch_bounds__(512) void fixup(
    const int* __restrict__ x, const void* __restrict__ emb,
    const void* __restrict__ Ww, const void* __restrict__ Wb,
    const void* __restrict__ Uw, const void* __restrict__ Ub,
    const void* __restrict__ Vw, const void* __restrict__ Vb,
    void* __restrict__ out, int force)
{
    __shared__ float h_s[2][B_PER][HID];
    __shared__ float xe_sf[B_PER][EMB];
    __shared__ int   flags_s, bad_s;

    const int tid = threadIdx.x;
    const int b0  = blockIdx.x * B_PER;

    if (tid == 0) {
        int fl = detect_flags(x, emb);
        flags_s = fl;
        int bad = force;
        if (!force) {
            bool f32o = (fl & 1) != 0;
            for (int i = 0; i < 2 * B_PER; ++i) {
                int oi = b0 * 2 + i;
                if (f32o) {
                    float v = ((const float*)out)[oi];
                    bad |= (v != v);
                } else {
                    unsigned short u = ((const unsigned short*)out)[oi];
                    bad |= (((u & 0x7F80u) == 0x7F80u) && ((u & 0x7Fu) != 0));
                }
            }
        }
        bad_s = bad;
    }
    __syncthreads();
    if (!bad_s) return;

    const bool f32w = (flags_s & 1) != 0;
    const bool x64  = (flags_s & 2) != 0;
    const int n = tid;
    const float bias = ldf(Wb, n, f32w) + ldf(Ub, n, f32w);

    for (int b = 0; b < B_PER; ++b) h_s[0][b][n] = 0.0f;

    for (int t = 0; t < T_STEPS; ++t) {
        {
            int b = tid >> 8, c = tid & 255;
            int tok = get_tok(x, (b0 + b) * T_STEPS + t, x64);
            xe_sf[b][c] = ldf(emb, (long)tok * EMB + c, f32w);
        }
        __syncthreads();

        float acc0 = bias, acc1 = bias;
        const long wrow = (long)n * EMB;
#pragma unroll 8
        for (int k = 0; k < EMB; ++k) {
            float wv = ldf(Ww, wrow + k, f32w);
            acc0 += xe_sf[0][k] * wv;
            acc1 += xe_sf[1][k] * wv;
        }
        const long urow = (long)n * HID;
        const float* hc0 = h_s[t & 1][0];
        const float* hc1 = h_s[t & 1][1];
#pragma unroll 8
        for (int k = 0; k < HID; ++k) {
            float uv = ldf(Uw, urow + k, f32w);
            acc0 += hc0[k] * uv;
            acc1 += hc1[k] * uv;
        }
        h_s[(t + 1) & 1][0][n] = tanhf(acc0);
        h_s[(t + 1) & 1][1][n] = tanhf(acc1);
        __syncthreads();
    }

    if (tid < 2 * B_PER) {
        int b = tid >> 1, o = tid & 1;
        float s = ldf(Vb, o, f32w);
        for (int k = 0; k < HID; ++k)
            s += h_s[0][b][k] * ldf(Vw, (long)o * HID + k, f32w);
        stf(out, (b0 + b) * 2 + o, s, f32w);
    }
}

extern "C" void kernel_launch(void* const* d_in, const int* in_sizes, int n_in,
                              void* d_out, int out_size, void* d_ws, size_t ws_size,
                              hipStream_t stream) {
    const int* x = (const int*)d_in[0];
    const size_t WX16 = (size_t)T_STEPS * 128 * 512 * 2;   // 64 MB bf16
    if (ws_size >= WX16) {
        wx_gemm<<<512, 1024, 0, stream>>>(
            x, d_in[1], d_in[2], d_in[3], d_in[5], (unsigned char*)d_ws);
        scan_i8<<<8, 1024, 0, stream>>>(
            d_in[4], d_in[6], d_in[7], x, d_in[1],
            (const unsigned char*)d_ws, d_out);
        fixup<<<64, 512, 0, stream>>>(
            x, d_in[1], d_in[2], d_in[3], d_in[4], d_in[5], d_in[6], d_in[7],
            d_out, 0);
    } else if (ws_size >= (size_t)R7_WS_NEED) {
        hipMemsetAsync(d_ws, 0, 4096, stream);
        scan_mfma_fb<<<32, 256, 0, stream>>>(
            x, d_in[1], d_in[2], d_in[3], d_in[4], d_in[5], d_in[6], d_in[7],
            (unsigned char*)d_ws, d_out);
        fixup<<<64, 512, 0, stream>>>(
            x, d_in[1], d_in[2], d_in[3], d_in[4], d_in[5], d_in[6], d_in[7],
            d_out, 0);
    } else {
        fixup<<<64, 512, 0, stream>>>(
            x, d_in[1], d_in[2], d_in[3], d_in[4], d_in[5], d_in[6], d_in[7],
            d_out, 1);
    }
}